// Round 12
// baseline (383.427 us; speedup 1.0000x reference)
//
#include <hip/hip_runtime.h>
#include <hip/hip_bf16.h>
#include <math.h>

#define NNODES 100000
#define NEDGES 3200000
constexpr int NCHB = (NNODES + 255) / 256; // 391 buckets of 256 nodes
constexpr int NBLK = 256;                  // partition blocks
constexpr int Q4PB = (NEDGES / 4) / NBLK;  // 3125 int4 per block (exact)

typedef __hip_bfloat16 bf16;
__device__ __forceinline__ bf16 f2b(float v) { return __float2bfloat16(v); }
__device__ __forceinline__ float b2f(bf16 v) { return __bfloat162float(v); }
__device__ __forceinline__ float lo2f(unsigned u) { return __uint_as_float(u << 16); }
__device__ __forceinline__ float hi2f(unsigned u) { return __uint_as_float(u & 0xffff0000u); }

// 8-way compile-time-tree select: returns a[c], c in 0..7
__device__ __forceinline__ float sel8(int c, float a0, float a1, float a2, float a3,
                                      float a4, float a5, float a6, float a7) {
    float b0 = (c & 1) ? a1 : a0, b2 = (c & 1) ? a3 : a2;
    float b4 = (c & 1) ? a5 : a4, b6 = (c & 1) ? a7 : a6;
    float c0 = (c & 2) ? b2 : b0, c4 = (c & 2) ? b6 : b4;
    return (c & 4) ? c4 : c0;
}

// ---------------- CSR build: one-pass radix partition by dst>>8 ----------------

__global__ __launch_bounds__(256) void k_hist2(const int4* __restrict__ dst4,
                                               int* __restrict__ histT,
                                               int* __restrict__ bs) {
    __shared__ int h[NCHB];
    int tid = threadIdx.x, blk = blockIdx.x;
    for (int i = tid; i < NCHB; i += 256) h[i] = 0;
    __syncthreads();
    int base = blk * Q4PB;
    for (int i = tid; i < Q4PB; i += 256) {
        int4 d = dst4[base + i];
        atomicAdd(&h[d.x >> 8], 1);
        atomicAdd(&h[d.y >> 8], 1);
        atomicAdd(&h[d.z >> 8], 1);
        atomicAdd(&h[d.w >> 8], 1);
    }
    __syncthreads();
    for (int i = tid; i < NCHB; i += 256) {
        int v = h[i];
        histT[i * NBLK + blk] = v;
        if (v) atomicAdd(&bs[i], v);   // no result needed -> pipelines
    }
}

__global__ void k_scanbs(const int* __restrict__ bs, int* __restrict__ bse,
                         int* __restrict__ offs) {
    __shared__ int s[512];
    int i = threadIdx.x;
    int v = (i < NCHB) ? bs[i] : 0;
    s[i] = v;
    __syncthreads();
    for (int off = 1; off < 512; off <<= 1) {
        int t = (i >= off) ? s[i - off] : 0;
        __syncthreads();
        s[i] += t;
        __syncthreads();
    }
    if (i < NCHB) bse[i] = s[i] - v;  // exclusive
    if (i == 0) { bse[NCHB] = NEDGES; offs[NNODES] = NEDGES; }
}

__global__ __launch_bounds__(256) void k_scanhist(int* __restrict__ histT,
                                                  const int* __restrict__ bse) {
    int b = blockIdx.x, tid = threadIdx.x;
    int lane = tid & 63, wid = tid >> 6;
    int d = histT[b * NBLK + tid];
    int v = d;  // inclusive wave scan
    { int t = __shfl_up(v, 1);  if (lane >= 1)  v += t; }
    { int t = __shfl_up(v, 2);  if (lane >= 2)  v += t; }
    { int t = __shfl_up(v, 4);  if (lane >= 4)  v += t; }
    { int t = __shfl_up(v, 8);  if (lane >= 8)  v += t; }
    { int t = __shfl_up(v, 16); if (lane >= 16) v += t; }
    { int t = __shfl_up(v, 32); if (lane >= 32) v += t; }
    __shared__ int ws[4];
    if (lane == 63) ws[wid] = v;
    __syncthreads();
    int woff = 0;
#pragma unroll
    for (int i = 0; i < 4; i++) woff += (i < wid) ? ws[i] : 0;
    histT[b * NBLK + tid] = bse[b] + woff + v - d;   // exclusive global base
}

__global__ __launch_bounds__(256) void k_scatter2(const int4* __restrict__ src4,
                                                  const int4* __restrict__ dst4,
                                                  const int* __restrict__ histT,
                                                  int* __restrict__ tmp) {
    __shared__ int cur[NCHB];
    int tid = threadIdx.x, blk = blockIdx.x;
    for (int i = tid; i < NCHB; i += 256) cur[i] = histT[i * NBLK + blk];
    __syncthreads();
    int base = blk * Q4PB;
    for (int i = tid; i < Q4PB; i += 256) {
        int4 s = src4[base + i];
        int4 d = dst4[base + i];
        int b, p;
        b = d.x >> 8; p = atomicAdd(&cur[b], 1); tmp[p] = ((d.x & 255) << 17) | s.x;
        b = d.y >> 8; p = atomicAdd(&cur[b], 1); tmp[p] = ((d.y & 255) << 17) | s.y;
        b = d.z >> 8; p = atomicAdd(&cur[b], 1); tmp[p] = ((d.z & 255) << 17) | s.z;
        b = d.w >> 8; p = atomicAdd(&cur[b], 1); tmp[p] = ((d.w & 255) << 17) | s.w;
    }
}

__global__ __launch_bounds__(256) void k_bucket(const int* __restrict__ tmp,
                                                const int* __restrict__ bse,
                                                int* __restrict__ offs,
                                                float* __restrict__ deginv,
                                                int* __restrict__ csr) {
    int b = blockIdx.x, tid = threadIdx.x;
    int lane = tid & 63, wid = tid >> 6;
    __shared__ int cnt[256], soff[256], ws[4];
    cnt[tid] = 0;
    __syncthreads();
    int s0 = bse[b], s1 = bse[b + 1];
    for (int i = s0 + tid; i < s1; i += 256) atomicAdd(&cnt[tmp[i] >> 17], 1);
    __syncthreads();
    int d = cnt[tid];
    int v = d;  // inclusive wave scan
    { int t = __shfl_up(v, 1);  if (lane >= 1)  v += t; }
    { int t = __shfl_up(v, 2);  if (lane >= 2)  v += t; }
    { int t = __shfl_up(v, 4);  if (lane >= 4)  v += t; }
    { int t = __shfl_up(v, 8);  if (lane >= 8)  v += t; }
    { int t = __shfl_up(v, 16); if (lane >= 16) v += t; }
    { int t = __shfl_up(v, 32); if (lane >= 32) v += t; }
    if (lane == 63) ws[wid] = v;
    __syncthreads();
    int woff = 0;
#pragma unroll
    for (int i = 0; i < 4; i++) woff += (i < wid) ? ws[i] : 0;
    int excl = woff + v - d;
    soff[tid] = excl;
    int node = b * 256 + tid;
    if (node < NNODES) {
        offs[node] = s0 + excl;
        deginv[node] = 1.0f / (float)max(d, 1);
    }
    cnt[tid] = 0;
    __syncthreads();
    for (int i = s0 + tid; i < s1; i += 256) {
        int e = tmp[i];
        int dl = e >> 17, src = e & 0x1FFFF;
        int slot = atomicAdd(&cnt[dl], 1);
        csr[s0 + soff[dl] + slot] = src;
    }
}

// ---- Gather 1: x-gather + w1 matvec + BN/ReLU -> h1 (bf16). Low VGPR, max TLP. ----

__global__ __launch_bounds__(64) void k_gather1(
    const float* __restrict__ x, const int* __restrict__ csr,
    const int* __restrict__ offs, const float* __restrict__ deginv,
    const float* __restrict__ w1l, const float* __restrict__ w1r,
    const float* __restrict__ b1,
    const float* __restrict__ g1, const float* __restrict__ bb1,
    const float* __restrict__ m1, const float* __restrict__ v1,
    bf16* __restrict__ h1b)
{
    int lane = threadIdx.x;
    float k1 = g1[lane] * rsqrtf(v1[lane] + 1e-5f);
    float c1 = (b1[lane] - m1[lane]) * k1 + bb1[lane];
    float w1lr[8], w1rr[8];
#pragma unroll
    for (int k = 0; k < 8; k++) {
        w1lr[k] = w1l[k * 64 + lane] * k1;
        w1rr[k] = w1r[k * 64 + lane] * k1;
    }

    const float4* xv = (const float4*)x;
    int fh = lane & 1;       // half-row: features 4*fh..4*fh+3
    int g  = lane >> 1;      // 32 edge slots

    for (int node = blockIdx.x; node < NNODES; node += gridDim.x) {
        int start = offs[node];
        int d = offs[node + 1] - start;
        int dl = min(d, 64);
        int c = csr[start + lane];                 // csr padded +64
        float xs = x[node * 8 + (lane & 7)];

        int s0 = __shfl(c, g), s1 = __shfl(c, g + 32);
        float4 w0 = xv[(size_t)((g      < dl) ? s0 : 0) * 2 + fh];
        float4 w1v = xv[(size_t)((g + 32 < dl) ? s1 : 0) * 2 + fh];
        float m0 = (g < dl) ? 1.f : 0.f;
        float m1f = (g + 32 < dl) ? 1.f : 0.f;
        float ax = m0 * w0.x + m1f * w1v.x;
        float ay = m0 * w0.y + m1f * w1v.y;
        float az = m0 * w0.z + m1f * w1v.z;
        float aw = m0 * w0.w + m1f * w1v.w;
        for (int i = g + 64; i < d; i += 32) {     // rare tail
            int s = csr[start + i];
            float4 w = xv[(size_t)s * 2 + fh];
            ax += w.x; ay += w.y; az += w.z; aw += w.w;
        }
#define RED1(X) X += __shfl_xor(X, 2); X += __shfl_xor(X, 4); X += __shfl_xor(X, 8); \
                X += __shfl_xor(X, 16); X += __shfl_xor(X, 32);
        RED1(ax) RED1(ay) RED1(az) RED1(aw)
#undef RED1
        float di = deginv[node];
        ax *= di; ay *= di; az *= di; aw *= di;

        float h = c1;
#pragma unroll
        for (int k = 0; k < 8; k++) {
            float comp = ((k & 3) == 0) ? ax : ((k & 3) == 1) ? ay : ((k & 3) == 2) ? az : aw;
            float a  = __shfl(comp, k >> 2);
            float xr = __shfl(xs, k);
            h = fmaf(a, w1lr[k], fmaf(xr, w1rr[k], h));
        }
        h1b[(size_t)node * 64 + lane] = f2b(fmaxf(h, 0.f));
    }
}

// ---- Dense 1: h1 -> t2 = h1@(w2l*k2) bf16, r2 = h1@(w2r*k2)+c2 fp32. VALU-bound. ----

__global__ __launch_bounds__(64, 2) void k_dense1(
    const bf16* __restrict__ h1b,
    const float* __restrict__ w2l, const float* __restrict__ w2r,
    const float* __restrict__ b2,
    const float* __restrict__ g2, const float* __restrict__ bb2,
    const float* __restrict__ m2, const float* __restrict__ v2,
    bf16* __restrict__ t2, float* __restrict__ r2)
{
    int lane = threadIdx.x;
    float k2 = g2[lane] * rsqrtf(v2[lane] + 1e-5f);
    float c2 = (b2[lane] - m2[lane]) * k2 + bb2[lane];
    float w2lr[64], w2rr[64];
#pragma unroll
    for (int k = 0; k < 64; k++) {
        w2lr[k] = w2l[k * 64 + lane] * k2;
        w2rr[k] = w2r[k * 64 + lane] * k2;
    }

    for (int node = blockIdx.x; node < NNODES; node += gridDim.x) {
        float h = b2f(h1b[(size_t)node * 64 + lane]);
        float tt = 0.f, rr = c2;
#pragma unroll
        for (int k = 0; k < 64; k++) {
            float hv = __shfl(h, k);      // compile-time lane -> v_readlane
            tt = fmaf(hv, w2lr[k], tt);
            rr = fmaf(hv, w2rr[k], rr);
        }
        t2[(size_t)node * 64 + lane] = f2b(tt);
        r2[(size_t)node * 64 + lane] = rr;
    }
}

// ---- Gather 2: t2-gather + r2 + ReLU -> h2 (bf16). Low VGPR, max TLP. ----

__global__ __launch_bounds__(64) void k_gather2(
    const bf16* __restrict__ t2, const float* __restrict__ r2,
    const int* __restrict__ csr, const int* __restrict__ offs,
    const float* __restrict__ deginv,
    bf16* __restrict__ h2b)
{
    int lane = threadIdx.x;
    int fq = lane & 7;       // feature octet
    int g  = lane >> 3;      // 8 edge slots
    const uint4* t2v = (const uint4*)t2;

    for (int node = blockIdx.x; node < NNODES; node += gridDim.x) {
        int start = offs[node];
        int d = offs[node + 1] - start;
        int dl = min(d, 64);
        int c = csr[start + lane];
        float r2v = r2[(size_t)node * 64 + lane];
        float di = deginv[node];

        int s;
        s = __shfl(c, g     ); uint4 w0 = t2v[(size_t)((g      < dl) ? s : 0) * 8 + fq];
        s = __shfl(c, g +  8); uint4 w1 = t2v[(size_t)((g +  8 < dl) ? s : 0) * 8 + fq];
        s = __shfl(c, g + 16); uint4 w2 = t2v[(size_t)((g + 16 < dl) ? s : 0) * 8 + fq];
        s = __shfl(c, g + 24); uint4 w3 = t2v[(size_t)((g + 24 < dl) ? s : 0) * 8 + fq];
        s = __shfl(c, g + 32); uint4 w4 = t2v[(size_t)((g + 32 < dl) ? s : 0) * 8 + fq];
        s = __shfl(c, g + 40); uint4 w5 = t2v[(size_t)((g + 40 < dl) ? s : 0) * 8 + fq];
        s = __shfl(c, g + 48); uint4 w6 = t2v[(size_t)((g + 48 < dl) ? s : 0) * 8 + fq];
        s = __shfl(c, g + 56); uint4 w7 = t2v[(size_t)((g + 56 < dl) ? s : 0) * 8 + fq];

        float a0 = 0, a1 = 0, a2 = 0, a3 = 0, a4 = 0, a5 = 0, a6 = 0, a7 = 0;
#define CONS(W, M) \
        a0 = fmaf(M, lo2f(W.x), a0); a1 = fmaf(M, hi2f(W.x), a1); \
        a2 = fmaf(M, lo2f(W.y), a2); a3 = fmaf(M, hi2f(W.y), a3); \
        a4 = fmaf(M, lo2f(W.z), a4); a5 = fmaf(M, hi2f(W.z), a5); \
        a6 = fmaf(M, lo2f(W.w), a6); a7 = fmaf(M, hi2f(W.w), a7);
        CONS(w0, (g      < dl) ? 1.f : 0.f)
        CONS(w1, (g +  8 < dl) ? 1.f : 0.f)
        CONS(w2, (g + 16 < dl) ? 1.f : 0.f)
        CONS(w3, (g + 24 < dl) ? 1.f : 0.f)
        CONS(w4, (g + 32 < dl) ? 1.f : 0.f)
        CONS(w5, (g + 40 < dl) ? 1.f : 0.f)
        CONS(w6, (g + 48 < dl) ? 1.f : 0.f)
        CONS(w7, (g + 56 < dl) ? 1.f : 0.f)
        for (int i = g + 64; i < d; i += 8) {       // rare tail
            int ss = csr[start + i];
            uint4 w = t2v[(size_t)ss * 8 + fq];
            CONS(w, 1.f)
        }
#undef CONS
#define RED2(X) X += __shfl_xor(X, 8); X += __shfl_xor(X, 16); X += __shfl_xor(X, 32);
        RED2(a0) RED2(a1) RED2(a2) RED2(a3) RED2(a4) RED2(a5) RED2(a6) RED2(a7)
#undef RED2
        float u = sel8(lane >> 3, a0, a1, a2, a3, a4, a5, a6, a7);
        int srcl = ((lane & 7) << 3) | (lane >> 3);
        float v = __shfl(u, srcl);

        h2b[(size_t)node * 64 + lane] = f2b(fmaxf(v * di + r2v, 0.f));
    }
}

// ---- Dense 2: h2 -> t3 = h2@w3l bf16 (lanes<32), r3 = h2@w3r+b3 fp32 (lanes>=32) ----

__global__ __launch_bounds__(64, 2) void k_dense2(
    const bf16* __restrict__ h2b,
    const float* __restrict__ w3l, const float* __restrict__ w3r,
    const float* __restrict__ b3,
    bf16* __restrict__ t3, float* __restrict__ r3)
{
    int lane = threadIdx.x;
    int j = lane & 31, half = lane >> 5;
    const float* wp = half ? w3r : w3l;
    float wcol[64];
#pragma unroll
    for (int k = 0; k < 64; k++) wcol[k] = wp[k * 32 + j];
    float b3v = half ? b3[j] : 0.f;

    for (int node = blockIdx.x; node < NNODES; node += gridDim.x) {
        float h = b2f(h2b[(size_t)node * 64 + lane]);
        float acc = b3v;
#pragma unroll
        for (int k = 0; k < 64; k++) {
            float hv = __shfl(h, k);
            acc = fmaf(hv, wcol[k], acc);
        }
        if (half == 0) t3[(size_t)node * 32 + j] = f2b(acc);
        else           r3[(size_t)node * 32 + j] = acc;
    }
}

// ---- Layer 3: gather t3 (bf16) -> relu(agg+r3) -> fc -> sigmoid ----

__global__ __launch_bounds__(256) void k_layer3(
    const bf16* __restrict__ t3, const float* __restrict__ r3,
    const int* __restrict__ csr, const int* __restrict__ offs,
    const float* __restrict__ deginv,
    const float* __restrict__ fcw, const float* __restrict__ fcb,
    float* __restrict__ out)
{
    int tid = threadIdx.x;
    int lane = tid & 63;
    int node = blockIdx.x * 4 + (tid >> 6);
    if (node >= NNODES) return;

    int o = lane & 31;
    float fcwv = fcw[o];
    float fcbv = fcb[0];

    int start = offs[node];
    int d = offs[node + 1] - start;
    int dl = min(d, 64);
    int c = csr[start + lane];
    float r3v = r3[(size_t)node * 32 + o];

    int fq = lane & 3;
    int g  = lane >> 2;
    const uint4* t3v = (const uint4*)t3;

    int   si[4];
    float mk[4];
#pragma unroll
    for (int t = 0; t < 4; t++) {
        int i = g + 16 * t;
        int s = __shfl(c, i);
        mk[t] = (i < dl) ? 1.f : 0.f;
        si[t] = (i < dl) ? s : 0;
    }
    uint4 w0 = t3v[(size_t)si[0] * 4 + fq];
    uint4 w1 = t3v[(size_t)si[1] * 4 + fq];
    uint4 w2 = t3v[(size_t)si[2] * 4 + fq];
    uint4 w3 = t3v[(size_t)si[3] * 4 + fq];

    float a0 = 0, a1 = 0, a2 = 0, a3 = 0, a4 = 0, a5 = 0, a6 = 0, a7 = 0;
#define CONS(W, M) \
    a0 = fmaf(M, lo2f(W.x), a0); a1 = fmaf(M, hi2f(W.x), a1); \
    a2 = fmaf(M, lo2f(W.y), a2); a3 = fmaf(M, hi2f(W.y), a3); \
    a4 = fmaf(M, lo2f(W.z), a4); a5 = fmaf(M, hi2f(W.z), a5); \
    a6 = fmaf(M, lo2f(W.w), a6); a7 = fmaf(M, hi2f(W.w), a7);
    CONS(w0, mk[0]) CONS(w1, mk[1]) CONS(w2, mk[2]) CONS(w3, mk[3])
    for (int i = g + 64; i < d; i += 16) {
        int s = csr[start + i];
        uint4 w = t3v[(size_t)s * 4 + fq];
        CONS(w, 1.f)
    }
#undef CONS
#define RED3(X) X += __shfl_xor(X, 4); X += __shfl_xor(X, 8); X += __shfl_xor(X, 16); X += __shfl_xor(X, 32);
    RED3(a0) RED3(a1) RED3(a2) RED3(a3) RED3(a4) RED3(a5) RED3(a6) RED3(a7)
#undef RED3
    float u = sel8((lane >> 2) & 7, a0, a1, a2, a3, a4, a5, a6, a7);
    int srcl = ((lane & 7) << 2) | ((lane >> 3) & 3);
    float v = __shfl(u, srcl);

    float h3 = fmaxf(v * deginv[node] + r3v, 0.f);

    float p = h3 * fcwv;
    p += __shfl_xor(p, 1);
    p += __shfl_xor(p, 2);
    p += __shfl_xor(p, 4);
    p += __shfl_xor(p, 8);
    p += __shfl_xor(p, 16);
    if (lane == 0) {
        float z = p + fcbv;
        out[node] = 1.0f / (1.0f + expf(-z));
    }
}

// ---------------- launch ----------------

extern "C" void kernel_launch(void* const* d_in, const int* in_sizes, int n_in,
                              void* d_out, int out_size, void* d_ws, size_t ws_size,
                              hipStream_t stream)
{
    const float* x   = (const float*)d_in[0];
    const int*   ei  = (const int*)d_in[1];
    const int*   src = ei;
    const int*   dst = ei + NEDGES;
    const float* w1l = (const float*)d_in[2];
    const float* w1r = (const float*)d_in[3];
    const float* b1  = (const float*)d_in[4];
    const float* g1  = (const float*)d_in[5];
    const float* bb1 = (const float*)d_in[6];
    const float* m1  = (const float*)d_in[7];
    const float* v1  = (const float*)d_in[8];
    const float* w2l = (const float*)d_in[9];
    const float* w2r = (const float*)d_in[10];
    const float* b2  = (const float*)d_in[11];
    const float* g2  = (const float*)d_in[12];
    const float* bb2 = (const float*)d_in[13];
    const float* m2  = (const float*)d_in[14];
    const float* v2  = (const float*)d_in[15];
    const float* w3l = (const float*)d_in[16];
    const float* w3r = (const float*)d_in[17];
    const float* b3  = (const float*)d_in[18];
    const float* fcw = (const float*)d_in[19];
    const float* fcb = (const float*)d_in[20];

    char* ws = (char*)d_ws;
    size_t off = 0;
    auto alloc = [&](size_t bytes) -> void* {
        void* p = ws + off;
        off += (bytes + 255) & ~(size_t)255;
        return p;
    };
    int*   offs   = (int*)alloc((size_t)(NNODES + 1) * 4);
    int*   bs     = (int*)alloc((size_t)NCHB * 4);
    int*   bse    = (int*)alloc((size_t)(NCHB + 1) * 4);
    int*   histT  = (int*)alloc((size_t)NCHB * NBLK * 4);
    float* deginv = (float*)alloc((size_t)NNODES * 4);
    int*   csr    = (int*)alloc((size_t)(NEDGES + 64) * 4);  // +64 pad
    bf16*  h1b    = (bf16*)alloc((size_t)NNODES * 64 * 2);
    bf16*  t2     = (bf16*)alloc((size_t)NNODES * 64 * 2);
    float* r2     = (float*)alloc((size_t)NNODES * 64 * 4);
    bf16*  h2b    = (bf16*)alloc((size_t)NNODES * 64 * 2);
    bf16*  t3     = (bf16*)alloc((size_t)NNODES * 32 * 2);
    float* r3     = (float*)alloc((size_t)NNODES * 32 * 4);
    int*   tmp    = (int*)r2;   // aliased: consumed by k_bucket before k_dense1 writes r2

    hipMemsetAsync(bs, 0, (size_t)NCHB * 4, stream);

    k_hist2<<<NBLK, 256, 0, stream>>>((const int4*)dst, histT, bs);
    k_scanbs<<<1, 512, 0, stream>>>(bs, bse, offs);
    k_scanhist<<<NCHB, 256, 0, stream>>>(histT, bse);
    k_scatter2<<<NBLK, 256, 0, stream>>>((const int4*)src, (const int4*)dst, histT, tmp);
    k_bucket<<<NCHB, 256, 0, stream>>>(tmp, bse, offs, deginv, csr);

    k_gather1<<<8192, 64, 0, stream>>>(x, csr, offs, deginv,
                                       w1l, w1r, b1, g1, bb1, m1, v1, h1b);
    k_dense1<<<2048, 64, 0, stream>>>(h1b, w2l, w2r, b2, g2, bb2, m2, v2, t2, r2);
    k_gather2<<<8192, 64, 0, stream>>>(t2, r2, csr, offs, deginv, h2b);
    k_dense2<<<2048, 64, 0, stream>>>(h2b, w3l, w3r, b3, t3, r3);
    k_layer3<<<(NNODES + 3) / 4, 256, 0, stream>>>(t3, r3, csr, offs, deginv,
                                                   fcw, fcb, (float*)d_out);
}

// Round 13
// 372.882 us; speedup vs baseline: 1.0283x; 1.0283x over previous
//
#include <hip/hip_runtime.h>
#include <hip/hip_bf16.h>
#include <math.h>

#define NNODES 100000
#define NEDGES 3200000
constexpr int NCHB = (NNODES + 255) / 256; // 391 buckets of 256 nodes
constexpr int NBLK = 256;                  // partition blocks
constexpr int Q4PB = (NEDGES / 4) / NBLK;  // 3125 int4 per block (exact)

typedef __hip_bfloat16 bf16;
__device__ __forceinline__ bf16 f2b(float v) { return __float2bfloat16(v); }
__device__ __forceinline__ float b2f(bf16 v) { return __bfloat162float(v); }
__device__ __forceinline__ float lo2f(unsigned u) { return __uint_as_float(u << 16); }
__device__ __forceinline__ float hi2f(unsigned u) { return __uint_as_float(u & 0xffff0000u); }

// 8-way compile-time-tree select: returns a[c], c in 0..7
__device__ __forceinline__ float sel8(int c, float a0, float a1, float a2, float a3,
                                      float a4, float a5, float a6, float a7) {
    float b0 = (c & 1) ? a1 : a0, b2 = (c & 1) ? a3 : a2;
    float b4 = (c & 1) ? a5 : a4, b6 = (c & 1) ? a7 : a6;
    float c0 = (c & 2) ? b2 : b0, c4 = (c & 2) ? b6 : b4;
    return (c & 4) ? c4 : c0;
}

// ---------------- CSR build: one-pass radix partition by dst>>8 ----------------

__global__ __launch_bounds__(256) void k_hist2(const int4* __restrict__ dst4,
                                               int* __restrict__ histT,
                                               int* __restrict__ bs) {
    __shared__ int h[NCHB];
    int tid = threadIdx.x, blk = blockIdx.x;
    for (int i = tid; i < NCHB; i += 256) h[i] = 0;
    __syncthreads();
    int base = blk * Q4PB;
    for (int i = tid; i < Q4PB; i += 256) {
        int4 d = dst4[base + i];
        atomicAdd(&h[d.x >> 8], 1);
        atomicAdd(&h[d.y >> 8], 1);
        atomicAdd(&h[d.z >> 8], 1);
        atomicAdd(&h[d.w >> 8], 1);
    }
    __syncthreads();
    for (int i = tid; i < NCHB; i += 256) {
        int v = h[i];
        histT[i * NBLK + blk] = v;
        if (v) atomicAdd(&bs[i], v);   // no result needed -> pipelines
    }
}

__global__ void k_scanbs(const int* __restrict__ bs, int* __restrict__ bse,
                         int* __restrict__ offs) {
    __shared__ int s[512];
    int i = threadIdx.x;
    int v = (i < NCHB) ? bs[i] : 0;
    s[i] = v;
    __syncthreads();
    for (int off = 1; off < 512; off <<= 1) {
        int t = (i >= off) ? s[i - off] : 0;
        __syncthreads();
        s[i] += t;
        __syncthreads();
    }
    if (i < NCHB) bse[i] = s[i] - v;  // exclusive
    if (i == 0) { bse[NCHB] = NEDGES; offs[NNODES] = NEDGES; }
}

__global__ __launch_bounds__(256) void k_scanhist(int* __restrict__ histT,
                                                  const int* __restrict__ bse) {
    int b = blockIdx.x, tid = threadIdx.x;
    int lane = tid & 63, wid = tid >> 6;
    int d = histT[b * NBLK + tid];
    int v = d;  // inclusive wave scan
    { int t = __shfl_up(v, 1);  if (lane >= 1)  v += t; }
    { int t = __shfl_up(v, 2);  if (lane >= 2)  v += t; }
    { int t = __shfl_up(v, 4);  if (lane >= 4)  v += t; }
    { int t = __shfl_up(v, 8);  if (lane >= 8)  v += t; }
    { int t = __shfl_up(v, 16); if (lane >= 16) v += t; }
    { int t = __shfl_up(v, 32); if (lane >= 32) v += t; }
    __shared__ int ws[4];
    if (lane == 63) ws[wid] = v;
    __syncthreads();
    int woff = 0;
#pragma unroll
    for (int i = 0; i < 4; i++) woff += (i < wid) ? ws[i] : 0;
    histT[b * NBLK + tid] = bse[b] + woff + v - d;   // exclusive global base
}

__global__ __launch_bounds__(256) void k_scatter2(const int4* __restrict__ src4,
                                                  const int4* __restrict__ dst4,
                                                  const int* __restrict__ histT,
                                                  int* __restrict__ tmp) {
    __shared__ int cur[NCHB];
    int tid = threadIdx.x, blk = blockIdx.x;
    for (int i = tid; i < NCHB; i += 256) cur[i] = histT[i * NBLK + blk];
    __syncthreads();
    int base = blk * Q4PB;
    for (int i = tid; i < Q4PB; i += 256) {
        int4 s = src4[base + i];
        int4 d = dst4[base + i];
        int b, p;
        b = d.x >> 8; p = atomicAdd(&cur[b], 1); tmp[p] = ((d.x & 255) << 17) | s.x;
        b = d.y >> 8; p = atomicAdd(&cur[b], 1); tmp[p] = ((d.y & 255) << 17) | s.y;
        b = d.z >> 8; p = atomicAdd(&cur[b], 1); tmp[p] = ((d.z & 255) << 17) | s.z;
        b = d.w >> 8; p = atomicAdd(&cur[b], 1); tmp[p] = ((d.w & 255) << 17) | s.w;
    }
}

__global__ __launch_bounds__(256) void k_bucket(const int* __restrict__ tmp,
                                                const int* __restrict__ bse,
                                                int* __restrict__ offs,
                                                float* __restrict__ deginv,
                                                int* __restrict__ csr) {
    int b = blockIdx.x, tid = threadIdx.x;
    int lane = tid & 63, wid = tid >> 6;
    __shared__ int cnt[256], soff[256], ws[4];
    cnt[tid] = 0;
    __syncthreads();
    int s0 = bse[b], s1 = bse[b + 1];
    for (int i = s0 + tid; i < s1; i += 256) atomicAdd(&cnt[tmp[i] >> 17], 1);
    __syncthreads();
    int d = cnt[tid];
    int v = d;  // inclusive wave scan
    { int t = __shfl_up(v, 1);  if (lane >= 1)  v += t; }
    { int t = __shfl_up(v, 2);  if (lane >= 2)  v += t; }
    { int t = __shfl_up(v, 4);  if (lane >= 4)  v += t; }
    { int t = __shfl_up(v, 8);  if (lane >= 8)  v += t; }
    { int t = __shfl_up(v, 16); if (lane >= 16) v += t; }
    { int t = __shfl_up(v, 32); if (lane >= 32) v += t; }
    if (lane == 63) ws[wid] = v;
    __syncthreads();
    int woff = 0;
#pragma unroll
    for (int i = 0; i < 4; i++) woff += (i < wid) ? ws[i] : 0;
    int excl = woff + v - d;
    soff[tid] = excl;
    int node = b * 256 + tid;
    if (node < NNODES) {
        offs[node] = s0 + excl;
        deginv[node] = 1.0f / (float)max(d, 1);
    }
    cnt[tid] = 0;
    __syncthreads();
    for (int i = s0 + tid; i < s1; i += 256) {
        int e = tmp[i];
        int dl = e >> 17, src = e & 0x1FFFF;
        int slot = atomicAdd(&cnt[dl], 1);
        csr[s0 + soff[dl] + slot] = src;
    }
}

// ---- Gather 1: x-gather + w1 matvec + BN/ReLU -> h1 (bf16). Low VGPR, max TLP. ----

__global__ __launch_bounds__(64) void k_gather1(
    const float* __restrict__ x, const int* __restrict__ csr,
    const int* __restrict__ offs, const float* __restrict__ deginv,
    const float* __restrict__ w1l, const float* __restrict__ w1r,
    const float* __restrict__ b1,
    const float* __restrict__ g1, const float* __restrict__ bb1,
    const float* __restrict__ m1, const float* __restrict__ v1,
    bf16* __restrict__ h1b)
{
    int lane = threadIdx.x;
    float k1 = g1[lane] * rsqrtf(v1[lane] + 1e-5f);
    float c1 = (b1[lane] - m1[lane]) * k1 + bb1[lane];
    float w1lr[8], w1rr[8];
#pragma unroll
    for (int k = 0; k < 8; k++) {
        w1lr[k] = w1l[k * 64 + lane] * k1;
        w1rr[k] = w1r[k * 64 + lane] * k1;
    }

    const float4* xv = (const float4*)x;
    int fh = lane & 1;       // half-row: features 4*fh..4*fh+3
    int g  = lane >> 1;      // 32 edge slots

    for (int node = blockIdx.x; node < NNODES; node += gridDim.x) {
        int start = offs[node];
        int d = offs[node + 1] - start;
        int dl = min(d, 64);
        int c = csr[start + lane];                 // csr padded +64
        float xs = x[node * 8 + (lane & 7)];

        int s0 = __shfl(c, g), s1 = __shfl(c, g + 32);
        float4 w0 = xv[(size_t)((g      < dl) ? s0 : 0) * 2 + fh];
        float4 w1v = xv[(size_t)((g + 32 < dl) ? s1 : 0) * 2 + fh];
        float m0 = (g < dl) ? 1.f : 0.f;
        float m1f = (g + 32 < dl) ? 1.f : 0.f;
        float ax = m0 * w0.x + m1f * w1v.x;
        float ay = m0 * w0.y + m1f * w1v.y;
        float az = m0 * w0.z + m1f * w1v.z;
        float aw = m0 * w0.w + m1f * w1v.w;
        for (int i = g + 64; i < d; i += 32) {     // rare tail
            int s = csr[start + i];
            float4 w = xv[(size_t)s * 2 + fh];
            ax += w.x; ay += w.y; az += w.z; aw += w.w;
        }
#define RED1(X) X += __shfl_xor(X, 2); X += __shfl_xor(X, 4); X += __shfl_xor(X, 8); \
                X += __shfl_xor(X, 16); X += __shfl_xor(X, 32);
        RED1(ax) RED1(ay) RED1(az) RED1(aw)
#undef RED1
        float di = deginv[node];
        ax *= di; ay *= di; az *= di; aw *= di;

        float h = c1;
#pragma unroll
        for (int k = 0; k < 8; k++) {
            float comp = ((k & 3) == 0) ? ax : ((k & 3) == 1) ? ay : ((k & 3) == 2) ? az : aw;
            float a  = __shfl(comp, k >> 2);
            float xr = __shfl(xs, k);
            h = fmaf(a, w1lr[k], fmaf(xr, w1rr[k], h));
        }
        h1b[(size_t)node * 64 + lane] = f2b(fmaxf(h, 0.f));
    }
}

// ---- Dense 1: h1 -> t2/r2, 2 nodes per iter (4 independent FMA chains) ----

__global__ __launch_bounds__(64, 2) void k_dense1(
    const bf16* __restrict__ h1b,
    const float* __restrict__ w2l, const float* __restrict__ w2r,
    const float* __restrict__ b2,
    const float* __restrict__ g2, const float* __restrict__ bb2,
    const float* __restrict__ m2, const float* __restrict__ v2,
    bf16* __restrict__ t2, float* __restrict__ r2)
{
    int lane = threadIdx.x;
    float k2 = g2[lane] * rsqrtf(v2[lane] + 1e-5f);
    float c2 = (b2[lane] - m2[lane]) * k2 + bb2[lane];
    float w2lr[64], w2rr[64];
#pragma unroll
    for (int k = 0; k < 64; k++) {
        w2lr[k] = w2l[k * 64 + lane] * k2;
        w2rr[k] = w2r[k * 64 + lane] * k2;
    }

    // NNODES even -> nA+1 always valid inside stride-2 loop
    for (int nA = blockIdx.x * 2; nA < NNODES; nA += gridDim.x * 2) {
        int nB = nA + 1;
        float hA = b2f(h1b[(size_t)nA * 64 + lane]);
        float hB = b2f(h1b[(size_t)nB * 64 + lane]);
        float ttA = 0.f, rrA = c2, ttB = 0.f, rrB = c2;
#pragma unroll
        for (int k = 0; k < 64; k++) {
            float hvA = __shfl(hA, k);    // compile-time lane -> v_readlane
            float hvB = __shfl(hB, k);
            ttA = fmaf(hvA, w2lr[k], ttA);
            rrA = fmaf(hvA, w2rr[k], rrA);
            ttB = fmaf(hvB, w2lr[k], ttB);
            rrB = fmaf(hvB, w2rr[k], rrB);
        }
        t2[(size_t)nA * 64 + lane] = f2b(ttA);
        r2[(size_t)nA * 64 + lane] = rrA;
        t2[(size_t)nB * 64 + lane] = f2b(ttB);
        r2[(size_t)nB * 64 + lane] = rrB;
    }
}

// ---- Gather 2: t2-gather + r2 + ReLU -> h2 (bf16). Low VGPR, max TLP. ----

__global__ __launch_bounds__(64) void k_gather2(
    const bf16* __restrict__ t2, const float* __restrict__ r2,
    const int* __restrict__ csr, const int* __restrict__ offs,
    const float* __restrict__ deginv,
    bf16* __restrict__ h2b)
{
    int lane = threadIdx.x;
    int fq = lane & 7;       // feature octet
    int g  = lane >> 3;      // 8 edge slots
    const uint4* t2v = (const uint4*)t2;

    for (int node = blockIdx.x; node < NNODES; node += gridDim.x) {
        int start = offs[node];
        int d = offs[node + 1] - start;
        int dl = min(d, 64);
        int c = csr[start + lane];
        float r2v = r2[(size_t)node * 64 + lane];
        float di = deginv[node];

        int s;
        s = __shfl(c, g     ); uint4 w0 = t2v[(size_t)((g      < dl) ? s : 0) * 8 + fq];
        s = __shfl(c, g +  8); uint4 w1 = t2v[(size_t)((g +  8 < dl) ? s : 0) * 8 + fq];
        s = __shfl(c, g + 16); uint4 w2 = t2v[(size_t)((g + 16 < dl) ? s : 0) * 8 + fq];
        s = __shfl(c, g + 24); uint4 w3 = t2v[(size_t)((g + 24 < dl) ? s : 0) * 8 + fq];
        s = __shfl(c, g + 32); uint4 w4 = t2v[(size_t)((g + 32 < dl) ? s : 0) * 8 + fq];
        s = __shfl(c, g + 40); uint4 w5 = t2v[(size_t)((g + 40 < dl) ? s : 0) * 8 + fq];
        s = __shfl(c, g + 48); uint4 w6 = t2v[(size_t)((g + 48 < dl) ? s : 0) * 8 + fq];
        s = __shfl(c, g + 56); uint4 w7 = t2v[(size_t)((g + 56 < dl) ? s : 0) * 8 + fq];

        float a0 = 0, a1 = 0, a2 = 0, a3 = 0, a4 = 0, a5 = 0, a6 = 0, a7 = 0;
#define CONS(W, M) \
        a0 = fmaf(M, lo2f(W.x), a0); a1 = fmaf(M, hi2f(W.x), a1); \
        a2 = fmaf(M, lo2f(W.y), a2); a3 = fmaf(M, hi2f(W.y), a3); \
        a4 = fmaf(M, lo2f(W.z), a4); a5 = fmaf(M, hi2f(W.z), a5); \
        a6 = fmaf(M, lo2f(W.w), a6); a7 = fmaf(M, hi2f(W.w), a7);
        CONS(w0, (g      < dl) ? 1.f : 0.f)
        CONS(w1, (g +  8 < dl) ? 1.f : 0.f)
        CONS(w2, (g + 16 < dl) ? 1.f : 0.f)
        CONS(w3, (g + 24 < dl) ? 1.f : 0.f)
        CONS(w4, (g + 32 < dl) ? 1.f : 0.f)
        CONS(w5, (g + 40 < dl) ? 1.f : 0.f)
        CONS(w6, (g + 48 < dl) ? 1.f : 0.f)
        CONS(w7, (g + 56 < dl) ? 1.f : 0.f)
        for (int i = g + 64; i < d; i += 8) {       // rare tail
            int ss = csr[start + i];
            uint4 w = t2v[(size_t)ss * 8 + fq];
            CONS(w, 1.f)
        }
#undef CONS
#define RED2(X) X += __shfl_xor(X, 8); X += __shfl_xor(X, 16); X += __shfl_xor(X, 32);
        RED2(a0) RED2(a1) RED2(a2) RED2(a3) RED2(a4) RED2(a5) RED2(a6) RED2(a7)
#undef RED2
        float u = sel8(lane >> 3, a0, a1, a2, a3, a4, a5, a6, a7);
        int srcl = ((lane & 7) << 3) | (lane >> 3);
        float v = __shfl(u, srcl);

        h2b[(size_t)node * 64 + lane] = f2b(fmaxf(v * di + r2v, 0.f));
    }
}

// ---- Dense 2: h2 -> t3/r3, 4 nodes per iter (4 independent FMA chains) ----

__global__ __launch_bounds__(64, 4) void k_dense2(
    const bf16* __restrict__ h2b,
    const float* __restrict__ w3l, const float* __restrict__ w3r,
    const float* __restrict__ b3,
    bf16* __restrict__ t3, float* __restrict__ r3)
{
    int lane = threadIdx.x;
    int j = lane & 31, half = lane >> 5;
    const float* wp = half ? w3r : w3l;
    float wcol[64];
#pragma unroll
    for (int k = 0; k < 64; k++) wcol[k] = wp[k * 32 + j];
    float b3v = half ? b3[j] : 0.f;

    // NNODES % 4 == 0 -> nA..nA+3 always valid inside stride-4 loop
    for (int nA = blockIdx.x * 4; nA < NNODES; nA += gridDim.x * 4) {
        float h0 = b2f(h2b[(size_t)(nA + 0) * 64 + lane]);
        float h1 = b2f(h2b[(size_t)(nA + 1) * 64 + lane]);
        float h2 = b2f(h2b[(size_t)(nA + 2) * 64 + lane]);
        float h3 = b2f(h2b[(size_t)(nA + 3) * 64 + lane]);
        float a0 = b3v, a1 = b3v, a2 = b3v, a3 = b3v;
#pragma unroll
        for (int k = 0; k < 64; k++) {
            float w = wcol[k];
            a0 = fmaf(__shfl(h0, k), w, a0);
            a1 = fmaf(__shfl(h1, k), w, a1);
            a2 = fmaf(__shfl(h2, k), w, a2);
            a3 = fmaf(__shfl(h3, k), w, a3);
        }
        if (half == 0) {
            t3[(size_t)(nA + 0) * 32 + j] = f2b(a0);
            t3[(size_t)(nA + 1) * 32 + j] = f2b(a1);
            t3[(size_t)(nA + 2) * 32 + j] = f2b(a2);
            t3[(size_t)(nA + 3) * 32 + j] = f2b(a3);
        } else {
            r3[(size_t)(nA + 0) * 32 + j] = a0;
            r3[(size_t)(nA + 1) * 32 + j] = a1;
            r3[(size_t)(nA + 2) * 32 + j] = a2;
            r3[(size_t)(nA + 3) * 32 + j] = a3;
        }
    }
}

// ---- Layer 3: gather t3 (bf16) -> relu(agg+r3) -> fc -> sigmoid ----

__global__ __launch_bounds__(256) void k_layer3(
    const bf16* __restrict__ t3, const float* __restrict__ r3,
    const int* __restrict__ csr, const int* __restrict__ offs,
    const float* __restrict__ deginv,
    const float* __restrict__ fcw, const float* __restrict__ fcb,
    float* __restrict__ out)
{
    int tid = threadIdx.x;
    int lane = tid & 63;
    int node = blockIdx.x * 4 + (tid >> 6);
    if (node >= NNODES) return;

    int o = lane & 31;
    float fcwv = fcw[o];
    float fcbv = fcb[0];

    int start = offs[node];
    int d = offs[node + 1] - start;
    int dl = min(d, 64);
    int c = csr[start + lane];
    float r3v = r3[(size_t)node * 32 + o];

    int fq = lane & 3;
    int g  = lane >> 2;
    const uint4* t3v = (const uint4*)t3;

    int   si[4];
    float mk[4];
#pragma unroll
    for (int t = 0; t < 4; t++) {
        int i = g + 16 * t;
        int s = __shfl(c, i);
        mk[t] = (i < dl) ? 1.f : 0.f;
        si[t] = (i < dl) ? s : 0;
    }
    uint4 w0 = t3v[(size_t)si[0] * 4 + fq];
    uint4 w1 = t3v[(size_t)si[1] * 4 + fq];
    uint4 w2 = t3v[(size_t)si[2] * 4 + fq];
    uint4 w3 = t3v[(size_t)si[3] * 4 + fq];

    float a0 = 0, a1 = 0, a2 = 0, a3 = 0, a4 = 0, a5 = 0, a6 = 0, a7 = 0;
#define CONS(W, M) \
    a0 = fmaf(M, lo2f(W.x), a0); a1 = fmaf(M, hi2f(W.x), a1); \
    a2 = fmaf(M, lo2f(W.y), a2); a3 = fmaf(M, hi2f(W.y), a3); \
    a4 = fmaf(M, lo2f(W.z), a4); a5 = fmaf(M, hi2f(W.z), a5); \
    a6 = fmaf(M, lo2f(W.w), a6); a7 = fmaf(M, hi2f(W.w), a7);
    CONS(w0, mk[0]) CONS(w1, mk[1]) CONS(w2, mk[2]) CONS(w3, mk[3])
    for (int i = g + 64; i < d; i += 16) {
        int s = csr[start + i];
        uint4 w = t3v[(size_t)s * 4 + fq];
        CONS(w, 1.f)
    }
#undef CONS
#define RED3(X) X += __shfl_xor(X, 4); X += __shfl_xor(X, 8); X += __shfl_xor(X, 16); X += __shfl_xor(X, 32);
    RED3(a0) RED3(a1) RED3(a2) RED3(a3) RED3(a4) RED3(a5) RED3(a6) RED3(a7)
#undef RED3
    float u = sel8((lane >> 2) & 7, a0, a1, a2, a3, a4, a5, a6, a7);
    int srcl = ((lane & 7) << 2) | ((lane >> 3) & 3);
    float v = __shfl(u, srcl);

    float h3 = fmaxf(v * deginv[node] + r3v, 0.f);

    float p = h3 * fcwv;
    p += __shfl_xor(p, 1);
    p += __shfl_xor(p, 2);
    p += __shfl_xor(p, 4);
    p += __shfl_xor(p, 8);
    p += __shfl_xor(p, 16);
    if (lane == 0) {
        float z = p + fcbv;
        out[node] = 1.0f / (1.0f + expf(-z));
    }
}

// ---------------- launch ----------------

extern "C" void kernel_launch(void* const* d_in, const int* in_sizes, int n_in,
                              void* d_out, int out_size, void* d_ws, size_t ws_size,
                              hipStream_t stream)
{
    const float* x   = (const float*)d_in[0];
    const int*   ei  = (const int*)d_in[1];
    const int*   src = ei;
    const int*   dst = ei + NEDGES;
    const float* w1l = (const float*)d_in[2];
    const float* w1r = (const float*)d_in[3];
    const float* b1  = (const float*)d_in[4];
    const float* g1  = (const float*)d_in[5];
    const float* bb1 = (const float*)d_in[6];
    const float* m1  = (const float*)d_in[7];
    const float* v1  = (const float*)d_in[8];
    const float* w2l = (const float*)d_in[9];
    const float* w2r = (const float*)d_in[10];
    const float* b2  = (const float*)d_in[11];
    const float* g2  = (const float*)d_in[12];
    const float* bb2 = (const float*)d_in[13];
    const float* m2  = (const float*)d_in[14];
    const float* v2  = (const float*)d_in[15];
    const float* w3l = (const float*)d_in[16];
    const float* w3r = (const float*)d_in[17];
    const float* b3  = (const float*)d_in[18];
    const float* fcw = (const float*)d_in[19];
    const float* fcb = (const float*)d_in[20];

    char* ws = (char*)d_ws;
    size_t off = 0;
    auto alloc = [&](size_t bytes) -> void* {
        void* p = ws + off;
        off += (bytes + 255) & ~(size_t)255;
        return p;
    };
    int*   offs   = (int*)alloc((size_t)(NNODES + 1) * 4);
    int*   bs     = (int*)alloc((size_t)NCHB * 4);
    int*   bse    = (int*)alloc((size_t)(NCHB + 1) * 4);
    int*   histT  = (int*)alloc((size_t)NCHB * NBLK * 4);
    float* deginv = (float*)alloc((size_t)NNODES * 4);
    int*   csr    = (int*)alloc((size_t)(NEDGES + 64) * 4);  // +64 pad
    bf16*  h1b    = (bf16*)alloc((size_t)NNODES * 64 * 2);
    bf16*  t2     = (bf16*)alloc((size_t)NNODES * 64 * 2);
    float* r2     = (float*)alloc((size_t)NNODES * 64 * 4);
    bf16*  h2b    = (bf16*)alloc((size_t)NNODES * 64 * 2);
    bf16*  t3     = (bf16*)alloc((size_t)NNODES * 32 * 2);
    float* r3     = (float*)alloc((size_t)NNODES * 32 * 4);
    int*   tmp    = (int*)r2;   // aliased: consumed by k_bucket before k_dense1 writes r2

    hipMemsetAsync(bs, 0, (size_t)NCHB * 4, stream);

    k_hist2<<<NBLK, 256, 0, stream>>>((const int4*)dst, histT, bs);
    k_scanbs<<<1, 512, 0, stream>>>(bs, bse, offs);
    k_scanhist<<<NCHB, 256, 0, stream>>>(histT, bse);
    k_scatter2<<<NBLK, 256, 0, stream>>>((const int4*)src, (const int4*)dst, histT, tmp);
    k_bucket<<<NCHB, 256, 0, stream>>>(tmp, bse, offs, deginv, csr);

    k_gather1<<<8192, 64, 0, stream>>>(x, csr, offs, deginv,
                                       w1l, w1r, b1, g1, bb1, m1, v1, h1b);
    k_dense1<<<4096, 64, 0, stream>>>(h1b, w2l, w2r, b2, g2, bb2, m2, v2, t2, r2);
    k_gather2<<<8192, 64, 0, stream>>>(t2, r2, csr, offs, deginv, h2b);
    k_dense2<<<8192, 64, 0, stream>>>(h2b, w3l, w3r, b3, t3, r3);
    k_layer3<<<(NNODES + 3) / 4, 256, 0, stream>>>(t3, r3, csr, offs, deginv,
                                                   fcw, fcb, (float*)d_out);
}

// Round 14
// 245.634 us; speedup vs baseline: 1.5610x; 1.5180x over previous
//
#include <hip/hip_runtime.h>
#include <hip/hip_bf16.h>
#include <math.h>

#define NNODES 100000
#define NEDGES 3200000
constexpr int NCHB = (NNODES + 255) / 256; // 391 buckets of 256 nodes
constexpr int NBLK = 256;                  // partition blocks
constexpr int Q4PB = (NEDGES / 4) / NBLK;  // 3125 int4 per block (exact)

typedef __hip_bfloat16 bf16;
typedef __attribute__((ext_vector_type(8))) short bf16x8;
typedef __attribute__((ext_vector_type(4))) float f32x4;

__device__ __forceinline__ bf16 f2b(float v) { return __float2bfloat16(v); }
__device__ __forceinline__ float b2f(bf16 v) { return __bfloat162float(v); }
__device__ __forceinline__ short f2bs(float v) {
    bf16 b = __float2bfloat16(v);
    return *reinterpret_cast<short*>(&b);
}
__device__ __forceinline__ float lo2f(unsigned u) { return __uint_as_float(u << 16); }
__device__ __forceinline__ float hi2f(unsigned u) { return __uint_as_float(u & 0xffff0000u); }

// 8-way compile-time-tree select: returns a[c], c in 0..7
__device__ __forceinline__ float sel8(int c, float a0, float a1, float a2, float a3,
                                      float a4, float a5, float a6, float a7) {
    float b0 = (c & 1) ? a1 : a0, b2 = (c & 1) ? a3 : a2;
    float b4 = (c & 1) ? a5 : a4, b6 = (c & 1) ? a7 : a6;
    float c0 = (c & 2) ? b2 : b0, c4 = (c & 2) ? b6 : b4;
    return (c & 4) ? c4 : c0;
}

// ---------------- CSR build: one-pass radix partition by dst>>8 ----------------

__global__ __launch_bounds__(256) void k_hist2(const int4* __restrict__ dst4,
                                               int* __restrict__ histT,
                                               int* __restrict__ bs) {
    __shared__ int h[NCHB];
    int tid = threadIdx.x, blk = blockIdx.x;
    for (int i = tid; i < NCHB; i += 256) h[i] = 0;
    __syncthreads();
    int base = blk * Q4PB;
    for (int i = tid; i < Q4PB; i += 256) {
        int4 d = dst4[base + i];
        atomicAdd(&h[d.x >> 8], 1);
        atomicAdd(&h[d.y >> 8], 1);
        atomicAdd(&h[d.z >> 8], 1);
        atomicAdd(&h[d.w >> 8], 1);
    }
    __syncthreads();
    for (int i = tid; i < NCHB; i += 256) {
        int v = h[i];
        histT[i * NBLK + blk] = v;
        if (v) atomicAdd(&bs[i], v);   // no result needed -> pipelines
    }
}

__global__ void k_scanbs(const int* __restrict__ bs, int* __restrict__ bse,
                         int* __restrict__ offs) {
    __shared__ int s[512];
    int i = threadIdx.x;
    int v = (i < NCHB) ? bs[i] : 0;
    s[i] = v;
    __syncthreads();
    for (int off = 1; off < 512; off <<= 1) {
        int t = (i >= off) ? s[i - off] : 0;
        __syncthreads();
        s[i] += t;
        __syncthreads();
    }
    if (i < NCHB) bse[i] = s[i] - v;  // exclusive
    if (i == 0) { bse[NCHB] = NEDGES; offs[NNODES] = NEDGES; }
}

__global__ __launch_bounds__(256) void k_scanhist(int* __restrict__ histT,
                                                  const int* __restrict__ bse) {
    int b = blockIdx.x, tid = threadIdx.x;
    int lane = tid & 63, wid = tid >> 6;
    int d = histT[b * NBLK + tid];
    int v = d;  // inclusive wave scan
    { int t = __shfl_up(v, 1);  if (lane >= 1)  v += t; }
    { int t = __shfl_up(v, 2);  if (lane >= 2)  v += t; }
    { int t = __shfl_up(v, 4);  if (lane >= 4)  v += t; }
    { int t = __shfl_up(v, 8);  if (lane >= 8)  v += t; }
    { int t = __shfl_up(v, 16); if (lane >= 16) v += t; }
    { int t = __shfl_up(v, 32); if (lane >= 32) v += t; }
    __shared__ int ws[4];
    if (lane == 63) ws[wid] = v;
    __syncthreads();
    int woff = 0;
#pragma unroll
    for (int i = 0; i < 4; i++) woff += (i < wid) ? ws[i] : 0;
    histT[b * NBLK + tid] = bse[b] + woff + v - d;   // exclusive global base
}

__global__ __launch_bounds__(256) void k_scatter2(const int4* __restrict__ src4,
                                                  const int4* __restrict__ dst4,
                                                  const int* __restrict__ histT,
                                                  int* __restrict__ tmp) {
    __shared__ int cur[NCHB];
    int tid = threadIdx.x, blk = blockIdx.x;
    for (int i = tid; i < NCHB; i += 256) cur[i] = histT[i * NBLK + blk];
    __syncthreads();
    int base = blk * Q4PB;
    for (int i = tid; i < Q4PB; i += 256) {
        int4 s = src4[base + i];
        int4 d = dst4[base + i];
        int b, p;
        b = d.x >> 8; p = atomicAdd(&cur[b], 1); tmp[p] = ((d.x & 255) << 17) | s.x;
        b = d.y >> 8; p = atomicAdd(&cur[b], 1); tmp[p] = ((d.y & 255) << 17) | s.y;
        b = d.z >> 8; p = atomicAdd(&cur[b], 1); tmp[p] = ((d.z & 255) << 17) | s.z;
        b = d.w >> 8; p = atomicAdd(&cur[b], 1); tmp[p] = ((d.w & 255) << 17) | s.w;
    }
}

__global__ __launch_bounds__(256) void k_bucket(const int* __restrict__ tmp,
                                                const int* __restrict__ bse,
                                                int* __restrict__ offs,
                                                float* __restrict__ deginv,
                                                int* __restrict__ csr) {
    int b = blockIdx.x, tid = threadIdx.x;
    int lane = tid & 63, wid = tid >> 6;
    __shared__ int cnt[256], soff[256], ws[4];
    cnt[tid] = 0;
    __syncthreads();
    int s0 = bse[b], s1 = bse[b + 1];
    for (int i = s0 + tid; i < s1; i += 256) atomicAdd(&cnt[tmp[i] >> 17], 1);
    __syncthreads();
    int d = cnt[tid];
    int v = d;  // inclusive wave scan
    { int t = __shfl_up(v, 1);  if (lane >= 1)  v += t; }
    { int t = __shfl_up(v, 2);  if (lane >= 2)  v += t; }
    { int t = __shfl_up(v, 4);  if (lane >= 4)  v += t; }
    { int t = __shfl_up(v, 8);  if (lane >= 8)  v += t; }
    { int t = __shfl_up(v, 16); if (lane >= 16) v += t; }
    { int t = __shfl_up(v, 32); if (lane >= 32) v += t; }
    if (lane == 63) ws[wid] = v;
    __syncthreads();
    int woff = 0;
#pragma unroll
    for (int i = 0; i < 4; i++) woff += (i < wid) ? ws[i] : 0;
    int excl = woff + v - d;
    soff[tid] = excl;
    int node = b * 256 + tid;
    if (node < NNODES) {
        offs[node] = s0 + excl;
        deginv[node] = 1.0f / (float)max(d, 1);
    }
    cnt[tid] = 0;
    __syncthreads();
    for (int i = s0 + tid; i < s1; i += 256) {
        int e = tmp[i];
        int dl = e >> 17, src = e & 0x1FFFF;
        int slot = atomicAdd(&cnt[dl], 1);
        csr[s0 + soff[dl] + slot] = src;
    }
}

// ---- Gather 1: x-gather + w1 matvec + BN/ReLU -> h1 (bf16). Low VGPR, max TLP. ----

__global__ __launch_bounds__(64) void k_gather1(
    const float* __restrict__ x, const int* __restrict__ csr,
    const int* __restrict__ offs, const float* __restrict__ deginv,
    const float* __restrict__ w1l, const float* __restrict__ w1r,
    const float* __restrict__ b1,
    const float* __restrict__ g1, const float* __restrict__ bb1,
    const float* __restrict__ m1, const float* __restrict__ v1,
    bf16* __restrict__ h1b)
{
    int lane = threadIdx.x;
    float k1 = g1[lane] * rsqrtf(v1[lane] + 1e-5f);
    float c1 = (b1[lane] - m1[lane]) * k1 + bb1[lane];
    float w1lr[8], w1rr[8];
#pragma unroll
    for (int k = 0; k < 8; k++) {
        w1lr[k] = w1l[k * 64 + lane] * k1;
        w1rr[k] = w1r[k * 64 + lane] * k1;
    }

    const float4* xv = (const float4*)x;
    int fh = lane & 1;       // half-row: features 4*fh..4*fh+3
    int g  = lane >> 1;      // 32 edge slots

    for (int node = blockIdx.x; node < NNODES; node += gridDim.x) {
        int start = offs[node];
        int d = offs[node + 1] - start;
        int dl = min(d, 64);
        int c = csr[start + lane];                 // csr padded +64
        float xs = x[node * 8 + (lane & 7)];

        int s0 = __shfl(c, g), s1 = __shfl(c, g + 32);
        float4 w0 = xv[(size_t)((g      < dl) ? s0 : 0) * 2 + fh];
        float4 w1v = xv[(size_t)((g + 32 < dl) ? s1 : 0) * 2 + fh];
        float m0 = (g < dl) ? 1.f : 0.f;
        float m1f = (g + 32 < dl) ? 1.f : 0.f;
        float ax = m0 * w0.x + m1f * w1v.x;
        float ay = m0 * w0.y + m1f * w1v.y;
        float az = m0 * w0.z + m1f * w1v.z;
        float aw = m0 * w0.w + m1f * w1v.w;
        for (int i = g + 64; i < d; i += 32) {     // rare tail
            int s = csr[start + i];
            float4 w = xv[(size_t)s * 2 + fh];
            ax += w.x; ay += w.y; az += w.z; aw += w.w;
        }
#define RED1(X) X += __shfl_xor(X, 2); X += __shfl_xor(X, 4); X += __shfl_xor(X, 8); \
                X += __shfl_xor(X, 16); X += __shfl_xor(X, 32);
        RED1(ax) RED1(ay) RED1(az) RED1(aw)
#undef RED1
        float di = deginv[node];
        ax *= di; ay *= di; az *= di; aw *= di;

        float h = c1;
#pragma unroll
        for (int k = 0; k < 8; k++) {
            float comp = ((k & 3) == 0) ? ax : ((k & 3) == 1) ? ay : ((k & 3) == 2) ? az : aw;
            float a  = __shfl(comp, k >> 2);
            float xr = __shfl(xs, k);
            h = fmaf(a, w1lr[k], fmaf(xr, w1rr[k], h));
        }
        h1b[(size_t)node * 64 + lane] = f2b(fmaxf(h, 0.f));
    }
}

// ---- Dense 1 (MFMA): h1 (bf16) -> t2 = h1@(w2l*k2) bf16, r2 = h1@(w2r*k2)+c2 fp32 ----
// A frag: lane l holds h[tile16 + (l&15)][ (l>>4)*8 + j + kh*32 ], j=0..7 (one uint4)
// B frag: lane l holds W[ kh*32 + (l>>4)*8 + j ][ ct*16 + (l&15) ]
// D:      lane l, reg r -> row (l>>4)*4+r, col l&15   [HW-verified mapping]

__global__ __launch_bounds__(64, 2) void k_dense1(
    const bf16* __restrict__ h1b,
    const float* __restrict__ w2l, const float* __restrict__ w2r,
    const float* __restrict__ b2,
    const float* __restrict__ g2, const float* __restrict__ bb2,
    const float* __restrict__ m2, const float* __restrict__ v2,
    bf16* __restrict__ t2, float* __restrict__ r2)
{
    int lane = threadIdx.x;
    int cn = lane & 15, kg = lane >> 4;

    bf16x8 BL[4][2], BR[4][2];
    float c2c[4];
#pragma unroll
    for (int ct = 0; ct < 4; ct++) {
        int col = ct * 16 + cn;
        float k2 = g2[col] * rsqrtf(v2[col] + 1e-5f);
        c2c[ct] = (b2[col] - m2[col]) * k2 + bb2[col];
#pragma unroll
        for (int kh = 0; kh < 2; kh++) {
#pragma unroll
            for (int j = 0; j < 8; j++) {
                int k = kh * 32 + kg * 8 + j;
                BL[ct][kh][j] = f2bs(w2l[k * 64 + col] * k2);
                BR[ct][kh][j] = f2bs(w2r[k * 64 + col] * k2);
            }
        }
    }

    const uint4* hv = (const uint4*)h1b;   // row stride = 8 uint4 (64 bf16)
    int ntiles = NNODES / 16;              // 6250
    for (int t = blockIdx.x; t < ntiles; t += gridDim.x) {
        int row = t * 16 + cn;
        uint4 a0u = hv[(size_t)row * 8 + kg];
        uint4 a1u = hv[(size_t)row * 8 + 4 + kg];
        bf16x8 a0 = *reinterpret_cast<bf16x8*>(&a0u);
        bf16x8 a1 = *reinterpret_cast<bf16x8*>(&a1u);
#pragma unroll
        for (int ct = 0; ct < 4; ct++) {
            f32x4 accT = {0.f, 0.f, 0.f, 0.f};
            f32x4 accR = {c2c[ct], c2c[ct], c2c[ct], c2c[ct]};
            accT = __builtin_amdgcn_mfma_f32_16x16x32_bf16(a0, BL[ct][0], accT, 0, 0, 0);
            accT = __builtin_amdgcn_mfma_f32_16x16x32_bf16(a1, BL[ct][1], accT, 0, 0, 0);
            accR = __builtin_amdgcn_mfma_f32_16x16x32_bf16(a0, BR[ct][0], accR, 0, 0, 0);
            accR = __builtin_amdgcn_mfma_f32_16x16x32_bf16(a1, BR[ct][1], accR, 0, 0, 0);
#pragma unroll
            for (int r = 0; r < 4; r++) {
                int node = t * 16 + kg * 4 + r;
                int col  = ct * 16 + cn;
                t2[(size_t)node * 64 + col] = f2b(accT[r]);
                r2[(size_t)node * 64 + col] = accR[r];
            }
        }
    }
}

// ---- Gather 2: t2-gather + r2 + ReLU -> h2 (bf16). Low VGPR, max TLP. ----

__global__ __launch_bounds__(64) void k_gather2(
    const bf16* __restrict__ t2, const float* __restrict__ r2,
    const int* __restrict__ csr, const int* __restrict__ offs,
    const float* __restrict__ deginv,
    bf16* __restrict__ h2b)
{
    int lane = threadIdx.x;
    int fq = lane & 7;       // feature octet
    int g  = lane >> 3;      // 8 edge slots
    const uint4* t2v = (const uint4*)t2;

    for (int node = blockIdx.x; node < NNODES; node += gridDim.x) {
        int start = offs[node];
        int d = offs[node + 1] - start;
        int dl = min(d, 64);
        int c = csr[start + lane];
        float r2v = r2[(size_t)node * 64 + lane];
        float di = deginv[node];

        int s;
        s = __shfl(c, g     ); uint4 w0 = t2v[(size_t)((g      < dl) ? s : 0) * 8 + fq];
        s = __shfl(c, g +  8); uint4 w1 = t2v[(size_t)((g +  8 < dl) ? s : 0) * 8 + fq];
        s = __shfl(c, g + 16); uint4 w2 = t2v[(size_t)((g + 16 < dl) ? s : 0) * 8 + fq];
        s = __shfl(c, g + 24); uint4 w3 = t2v[(size_t)((g + 24 < dl) ? s : 0) * 8 + fq];
        s = __shfl(c, g + 32); uint4 w4 = t2v[(size_t)((g + 32 < dl) ? s : 0) * 8 + fq];
        s = __shfl(c, g + 40); uint4 w5 = t2v[(size_t)((g + 40 < dl) ? s : 0) * 8 + fq];
        s = __shfl(c, g + 48); uint4 w6 = t2v[(size_t)((g + 48 < dl) ? s : 0) * 8 + fq];
        s = __shfl(c, g + 56); uint4 w7 = t2v[(size_t)((g + 56 < dl) ? s : 0) * 8 + fq];

        float a0 = 0, a1 = 0, a2 = 0, a3 = 0, a4 = 0, a5 = 0, a6 = 0, a7 = 0;
#define CONS(W, M) \
        a0 = fmaf(M, lo2f(W.x), a0); a1 = fmaf(M, hi2f(W.x), a1); \
        a2 = fmaf(M, lo2f(W.y), a2); a3 = fmaf(M, hi2f(W.y), a3); \
        a4 = fmaf(M, lo2f(W.z), a4); a5 = fmaf(M, hi2f(W.z), a5); \
        a6 = fmaf(M, lo2f(W.w), a6); a7 = fmaf(M, hi2f(W.w), a7);
        CONS(w0, (g      < dl) ? 1.f : 0.f)
        CONS(w1, (g +  8 < dl) ? 1.f : 0.f)
        CONS(w2, (g + 16 < dl) ? 1.f : 0.f)
        CONS(w3, (g + 24 < dl) ? 1.f : 0.f)
        CONS(w4, (g + 32 < dl) ? 1.f : 0.f)
        CONS(w5, (g + 40 < dl) ? 1.f : 0.f)
        CONS(w6, (g + 48 < dl) ? 1.f : 0.f)
        CONS(w7, (g + 56 < dl) ? 1.f : 0.f)
        for (int i = g + 64; i < d; i += 8) {       // rare tail
            int ss = csr[start + i];
            uint4 w = t2v[(size_t)ss * 8 + fq];
            CONS(w, 1.f)
        }
#undef CONS
#define RED2(X) X += __shfl_xor(X, 8); X += __shfl_xor(X, 16); X += __shfl_xor(X, 32);
        RED2(a0) RED2(a1) RED2(a2) RED2(a3) RED2(a4) RED2(a5) RED2(a6) RED2(a7)
#undef RED2
        float u = sel8(lane >> 3, a0, a1, a2, a3, a4, a5, a6, a7);
        int srcl = ((lane & 7) << 3) | (lane >> 3);
        float v = __shfl(u, srcl);

        h2b[(size_t)node * 64 + lane] = f2b(fmaxf(v * di + r2v, 0.f));
    }
}

// ---- Dense 2 (MFMA): h2 (bf16) -> [t3 | r3] = h2 @ [w3l | w3r] (+b3 on r3) ----

__global__ __launch_bounds__(64, 2) void k_dense2(
    const bf16* __restrict__ h2b,
    const float* __restrict__ w3l, const float* __restrict__ w3r,
    const float* __restrict__ b3,
    bf16* __restrict__ t3, float* __restrict__ r3)
{
    int lane = threadIdx.x;
    int cn = lane & 15, kg = lane >> 4;

    bf16x8 Bf[4][2];
    float cini[4];
#pragma unroll
    for (int ct = 0; ct < 4; ct++) {
        int col = ct * 16 + cn;               // 0..63 over [w3l | w3r]
        const float* W = (ct < 2) ? w3l : w3r;
        int cc = col & 31;
        cini[ct] = (ct < 2) ? 0.f : b3[cc];
#pragma unroll
        for (int kh = 0; kh < 2; kh++) {
#pragma unroll
            for (int j = 0; j < 8; j++) {
                int k = kh * 32 + kg * 8 + j;
                Bf[ct][kh][j] = f2bs(W[k * 32 + cc]);
            }
        }
    }

    const uint4* hv = (const uint4*)h2b;
    int ntiles = NNODES / 16;
    for (int t = blockIdx.x; t < ntiles; t += gridDim.x) {
        int row = t * 16 + cn;
        uint4 a0u = hv[(size_t)row * 8 + kg];
        uint4 a1u = hv[(size_t)row * 8 + 4 + kg];
        bf16x8 a0 = *reinterpret_cast<bf16x8*>(&a0u);
        bf16x8 a1 = *reinterpret_cast<bf16x8*>(&a1u);
#pragma unroll
        for (int ct = 0; ct < 4; ct++) {
            f32x4 acc = {cini[ct], cini[ct], cini[ct], cini[ct]};
            acc = __builtin_amdgcn_mfma_f32_16x16x32_bf16(a0, Bf[ct][0], acc, 0, 0, 0);
            acc = __builtin_amdgcn_mfma_f32_16x16x32_bf16(a1, Bf[ct][1], acc, 0, 0, 0);
#pragma unroll
            for (int r = 0; r < 4; r++) {
                int node = t * 16 + kg * 4 + r;
                if (ct < 2) t3[(size_t)node * 32 + ct * 16 + cn] = f2b(acc[r]);
                else        r3[(size_t)node * 32 + (ct - 2) * 16 + cn] = acc[r];
            }
        }
    }
}

// ---- Layer 3: gather t3 (bf16) -> relu(agg+r3) -> fc -> sigmoid ----

__global__ __launch_bounds__(256) void k_layer3(
    const bf16* __restrict__ t3, const float* __restrict__ r3,
    const int* __restrict__ csr, const int* __restrict__ offs,
    const float* __restrict__ deginv,
    const float* __restrict__ fcw, const float* __restrict__ fcb,
    float* __restrict__ out)
{
    int tid = threadIdx.x;
    int lane = tid & 63;
    int node = blockIdx.x * 4 + (tid >> 6);
    if (node >= NNODES) return;

    int o = lane & 31;
    float fcwv = fcw[o];
    float fcbv = fcb[0];

    int start = offs[node];
    int d = offs[node + 1] - start;
    int dl = min(d, 64);
    int c = csr[start + lane];
    float r3v = r3[(size_t)node * 32 + o];

    int fq = lane & 3;
    int g  = lane >> 2;
    const uint4* t3v = (const uint4*)t3;

    int   si[4];
    float mk[4];
#pragma unroll
    for (int t = 0; t < 4; t++) {
        int i = g + 16 * t;
        int s = __shfl(c, i);
        mk[t] = (i < dl) ? 1.f : 0.f;
        si[t] = (i < dl) ? s : 0;
    }
    uint4 w0 = t3v[(size_t)si[0] * 4 + fq];
    uint4 w1 = t3v[(size_t)si[1] * 4 + fq];
    uint4 w2 = t3v[(size_t)si[2] * 4 + fq];
    uint4 w3 = t3v[(size_t)si[3] * 4 + fq];

    float a0 = 0, a1 = 0, a2 = 0, a3 = 0, a4 = 0, a5 = 0, a6 = 0, a7 = 0;
#define CONS(W, M) \
    a0 = fmaf(M, lo2f(W.x), a0); a1 = fmaf(M, hi2f(W.x), a1); \
    a2 = fmaf(M, lo2f(W.y), a2); a3 = fmaf(M, hi2f(W.y), a3); \
    a4 = fmaf(M, lo2f(W.z), a4); a5 = fmaf(M, hi2f(W.z), a5); \
    a6 = fmaf(M, lo2f(W.w), a6); a7 = fmaf(M, hi2f(W.w), a7);
    CONS(w0, mk[0]) CONS(w1, mk[1]) CONS(w2, mk[2]) CONS(w3, mk[3])
    for (int i = g + 64; i < d; i += 16) {
        int s = csr[start + i];
        uint4 w = t3v[(size_t)s * 4 + fq];
        CONS(w, 1.f)
    }
#undef CONS
#define RED3(X) X += __shfl_xor(X, 4); X += __shfl_xor(X, 8); X += __shfl_xor(X, 16); X += __shfl_xor(X, 32);
    RED3(a0) RED3(a1) RED3(a2) RED3(a3) RED3(a4) RED3(a5) RED3(a6) RED3(a7)
#undef RED3
    float u = sel8((lane >> 2) & 7, a0, a1, a2, a3, a4, a5, a6, a7);
    int srcl = ((lane & 7) << 2) | ((lane >> 3) & 3);
    float v = __shfl(u, srcl);

    float h3 = fmaxf(v * deginv[node] + r3v, 0.f);

    float p = h3 * fcwv;
    p += __shfl_xor(p, 1);
    p += __shfl_xor(p, 2);
    p += __shfl_xor(p, 4);
    p += __shfl_xor(p, 8);
    p += __shfl_xor(p, 16);
    if (lane == 0) {
        float z = p + fcbv;
        out[node] = 1.0f / (1.0f + expf(-z));
    }
}

// ---------------- launch ----------------

extern "C" void kernel_launch(void* const* d_in, const int* in_sizes, int n_in,
                              void* d_out, int out_size, void* d_ws, size_t ws_size,
                              hipStream_t stream)
{
    const float* x   = (const float*)d_in[0];
    const int*   ei  = (const int*)d_in[1];
    const int*   src = ei;
    const int*   dst = ei + NEDGES;
    const float* w1l = (const float*)d_in[2];
    const float* w1r = (const float*)d_in[3];
    const float* b1  = (const float*)d_in[4];
    const float* g1  = (const float*)d_in[5];
    const float* bb1 = (const float*)d_in[6];
    const float* m1  = (const float*)d_in[7];
    const float* v1  = (const float*)d_in[8];
    const float* w2l = (const float*)d_in[9];
    const float* w2r = (const float*)d_in[10];
    const float* b2  = (const float*)d_in[11];
    const float* g2  = (const float*)d_in[12];
    const float* bb2 = (const float*)d_in[13];
    const float* m2  = (const float*)d_in[14];
    const float* v2  = (const float*)d_in[15];
    const float* w3l = (const float*)d_in[16];
    const float* w3r = (const float*)d_in[17];
    const float* b3  = (const float*)d_in[18];
    const float* fcw = (const float*)d_in[19];
    const float* fcb = (const float*)d_in[20];

    char* ws = (char*)d_ws;
    size_t off = 0;
    auto alloc = [&](size_t bytes) -> void* {
        void* p = ws + off;
        off += (bytes + 255) & ~(size_t)255;
        return p;
    };
    int*   offs   = (int*)alloc((size_t)(NNODES + 1) * 4);
    int*   bs     = (int*)alloc((size_t)NCHB * 4);
    int*   bse    = (int*)alloc((size_t)(NCHB + 1) * 4);
    int*   histT  = (int*)alloc((size_t)NCHB * NBLK * 4);
    float* deginv = (float*)alloc((size_t)NNODES * 4);
    int*   csr    = (int*)alloc((size_t)(NEDGES + 64) * 4);  // +64 pad
    bf16*  h1b    = (bf16*)alloc((size_t)NNODES * 64 * 2);
    bf16*  t2     = (bf16*)alloc((size_t)NNODES * 64 * 2);
    float* r2     = (float*)alloc((size_t)NNODES * 64 * 4);
    bf16*  h2b    = (bf16*)alloc((size_t)NNODES * 64 * 2);
    bf16*  t3     = (bf16*)alloc((size_t)NNODES * 32 * 2);
    float* r3     = (float*)alloc((size_t)NNODES * 32 * 4);
    int*   tmp    = (int*)r2;   // aliased: consumed by k_bucket before k_dense1 writes r2

    hipMemsetAsync(bs, 0, (size_t)NCHB * 4, stream);

    k_hist2<<<NBLK, 256, 0, stream>>>((const int4*)dst, histT, bs);
    k_scanbs<<<1, 512, 0, stream>>>(bs, bse, offs);
    k_scanhist<<<NCHB, 256, 0, stream>>>(histT, bse);
    k_scatter2<<<NBLK, 256, 0, stream>>>((const int4*)src, (const int4*)dst, histT, tmp);
    k_bucket<<<NCHB, 256, 0, stream>>>(tmp, bse, offs, deginv, csr);

    k_gather1<<<8192, 64, 0, stream>>>(x, csr, offs, deginv,
                                       w1l, w1r, b1, g1, bb1, m1, v1, h1b);
    k_dense1<<<4096, 64, 0, stream>>>(h1b, w2l, w2r, b2, g2, bb2, m2, v2, t2, r2);
    k_gather2<<<8192, 64, 0, stream>>>(t2, r2, csr, offs, deginv, h2b);
    k_dense2<<<4096, 64, 0, stream>>>(h2b, w3l, w3r, b3, t3, r3);
    k_layer3<<<(NNODES + 3) / 4, 256, 0, stream>>>(t3, r3, csr, offs, deginv,
                                                   fcw, fcb, (float*)d_out);
}

// Round 15
// 243.785 us; speedup vs baseline: 1.5728x; 1.0076x over previous
//
#include <hip/hip_runtime.h>
#include <hip/hip_bf16.h>
#include <math.h>

#define NNODES 100000
#define NEDGES 3200000
constexpr int NCHB = (NNODES + 255) / 256; // 391 buckets of 256 nodes
constexpr int NBLK = 256;                  // partition blocks
constexpr int Q4PB = (NEDGES / 4) / NBLK;  // 3125 int4 per block (exact)

typedef __hip_bfloat16 bf16;
typedef __attribute__((ext_vector_type(8))) short bf16x8;
typedef __attribute__((ext_vector_type(4))) float f32x4;

__device__ __forceinline__ bf16 f2b(float v) { return __float2bfloat16(v); }
__device__ __forceinline__ float b2f(bf16 v) { return __bfloat162float(v); }
__device__ __forceinline__ short f2bs(float v) {
    bf16 b = __float2bfloat16(v);
    return *reinterpret_cast<short*>(&b);
}
__device__ __forceinline__ float lo2f(unsigned u) { return __uint_as_float(u << 16); }
__device__ __forceinline__ float hi2f(unsigned u) { return __uint_as_float(u & 0xffff0000u); }

// 8-way compile-time-tree select: returns a[c], c in 0..7
__device__ __forceinline__ float sel8(int c, float a0, float a1, float a2, float a3,
                                      float a4, float a5, float a6, float a7) {
    float b0 = (c & 1) ? a1 : a0, b2 = (c & 1) ? a3 : a2;
    float b4 = (c & 1) ? a5 : a4, b6 = (c & 1) ? a7 : a6;
    float c0 = (c & 2) ? b2 : b0, c4 = (c & 2) ? b6 : b4;
    return (c & 4) ? c4 : c0;
}

// ---------------- CSR build: one-pass radix partition by dst>>8 ----------------

__global__ __launch_bounds__(256) void k_hist2(const int4* __restrict__ dst4,
                                               int* __restrict__ histT,
                                               int* __restrict__ bs) {
    __shared__ int h[NCHB];
    int tid = threadIdx.x, blk = blockIdx.x;
    for (int i = tid; i < NCHB; i += 256) h[i] = 0;
    __syncthreads();
    int base = blk * Q4PB;
    for (int i = tid; i < Q4PB; i += 256) {
        int4 d = dst4[base + i];
        atomicAdd(&h[d.x >> 8], 1);
        atomicAdd(&h[d.y >> 8], 1);
        atomicAdd(&h[d.z >> 8], 1);
        atomicAdd(&h[d.w >> 8], 1);
    }
    __syncthreads();
    for (int i = tid; i < NCHB; i += 256) {
        int v = h[i];
        histT[i * NBLK + blk] = v;
        if (v) atomicAdd(&bs[i], v);   // no result needed -> pipelines
    }
}

__global__ void k_scanbs(const int* __restrict__ bs, int* __restrict__ bse,
                         int* __restrict__ offs) {
    __shared__ int s[512];
    int i = threadIdx.x;
    int v = (i < NCHB) ? bs[i] : 0;
    s[i] = v;
    __syncthreads();
    for (int off = 1; off < 512; off <<= 1) {
        int t = (i >= off) ? s[i - off] : 0;
        __syncthreads();
        s[i] += t;
        __syncthreads();
    }
    if (i < NCHB) bse[i] = s[i] - v;  // exclusive
    if (i == 0) { bse[NCHB] = NEDGES; offs[NNODES] = NEDGES; }
}

__global__ __launch_bounds__(256) void k_scanhist(int* __restrict__ histT,
                                                  const int* __restrict__ bse) {
    int b = blockIdx.x, tid = threadIdx.x;
    int lane = tid & 63, wid = tid >> 6;
    int d = histT[b * NBLK + tid];
    int v = d;  // inclusive wave scan
    { int t = __shfl_up(v, 1);  if (lane >= 1)  v += t; }
    { int t = __shfl_up(v, 2);  if (lane >= 2)  v += t; }
    { int t = __shfl_up(v, 4);  if (lane >= 4)  v += t; }
    { int t = __shfl_up(v, 8);  if (lane >= 8)  v += t; }
    { int t = __shfl_up(v, 16); if (lane >= 16) v += t; }
    { int t = __shfl_up(v, 32); if (lane >= 32) v += t; }
    __shared__ int ws[4];
    if (lane == 63) ws[wid] = v;
    __syncthreads();
    int woff = 0;
#pragma unroll
    for (int i = 0; i < 4; i++) woff += (i < wid) ? ws[i] : 0;
    histT[b * NBLK + tid] = bse[b] + woff + v - d;   // exclusive global base
}

__global__ __launch_bounds__(256) void k_scatter2(const int4* __restrict__ src4,
                                                  const int4* __restrict__ dst4,
                                                  const int* __restrict__ histT,
                                                  int* __restrict__ tmp) {
    __shared__ int cur[NCHB];
    int tid = threadIdx.x, blk = blockIdx.x;
    for (int i = tid; i < NCHB; i += 256) cur[i] = histT[i * NBLK + blk];
    __syncthreads();
    int base = blk * Q4PB;
    for (int i = tid; i < Q4PB; i += 256) {
        int4 s = src4[base + i];
        int4 d = dst4[base + i];
        int b, p;
        b = d.x >> 8; p = atomicAdd(&cur[b], 1); tmp[p] = ((d.x & 255) << 17) | s.x;
        b = d.y >> 8; p = atomicAdd(&cur[b], 1); tmp[p] = ((d.y & 255) << 17) | s.y;
        b = d.z >> 8; p = atomicAdd(&cur[b], 1); tmp[p] = ((d.z & 255) << 17) | s.z;
        b = d.w >> 8; p = atomicAdd(&cur[b], 1); tmp[p] = ((d.w & 255) << 17) | s.w;
    }
}

__global__ __launch_bounds__(256) void k_bucket(const int* __restrict__ tmp,
                                                const int* __restrict__ bse,
                                                int* __restrict__ offs,
                                                float* __restrict__ deginv,
                                                int* __restrict__ csr) {
    int b = blockIdx.x, tid = threadIdx.x;
    int lane = tid & 63, wid = tid >> 6;
    __shared__ int cnt[256], soff[256], ws[4];
    cnt[tid] = 0;
    __syncthreads();
    int s0 = bse[b], s1 = bse[b + 1];
    for (int i = s0 + tid; i < s1; i += 256) atomicAdd(&cnt[tmp[i] >> 17], 1);
    __syncthreads();
    int d = cnt[tid];
    int v = d;  // inclusive wave scan
    { int t = __shfl_up(v, 1);  if (lane >= 1)  v += t; }
    { int t = __shfl_up(v, 2);  if (lane >= 2)  v += t; }
    { int t = __shfl_up(v, 4);  if (lane >= 4)  v += t; }
    { int t = __shfl_up(v, 8);  if (lane >= 8)  v += t; }
    { int t = __shfl_up(v, 16); if (lane >= 16) v += t; }
    { int t = __shfl_up(v, 32); if (lane >= 32) v += t; }
    if (lane == 63) ws[wid] = v;
    __syncthreads();
    int woff = 0;
#pragma unroll
    for (int i = 0; i < 4; i++) woff += (i < wid) ? ws[i] : 0;
    int excl = woff + v - d;
    soff[tid] = excl;
    int node = b * 256 + tid;
    if (node < NNODES) {
        offs[node] = s0 + excl;
        deginv[node] = 1.0f / (float)max(d, 1);
    }
    cnt[tid] = 0;
    __syncthreads();
    for (int i = s0 + tid; i < s1; i += 256) {
        int e = tmp[i];
        int dl = e >> 17, src = e & 0x1FFFF;
        int slot = atomicAdd(&cnt[dl], 1);
        csr[s0 + soff[dl] + slot] = src;
    }
}

// ---- Gather 1: 4 waves/block, each wave one node. x-gather + w1 + BN/ReLU -> h1 ----

__global__ __launch_bounds__(256) void k_gather1(
    const float* __restrict__ x, const int* __restrict__ csr,
    const int* __restrict__ offs, const float* __restrict__ deginv,
    const float* __restrict__ w1l, const float* __restrict__ w1r,
    const float* __restrict__ b1,
    const float* __restrict__ g1, const float* __restrict__ bb1,
    const float* __restrict__ m1, const float* __restrict__ v1,
    bf16* __restrict__ h1b)
{
    int lane = threadIdx.x & 63, wid = threadIdx.x >> 6;
    float k1 = g1[lane] * rsqrtf(v1[lane] + 1e-5f);
    float c1 = (b1[lane] - m1[lane]) * k1 + bb1[lane];
    float w1lr[8], w1rr[8];
#pragma unroll
    for (int k = 0; k < 8; k++) {
        w1lr[k] = w1l[k * 64 + lane] * k1;
        w1rr[k] = w1r[k * 64 + lane] * k1;
    }

    const float4* xv = (const float4*)x;
    int fh = lane & 1;       // half-row: features 4*fh..4*fh+3
    int g  = lane >> 1;      // 32 edge slots

    for (int node = blockIdx.x * 4 + wid; node < NNODES; node += gridDim.x * 4) {
        int start = offs[node];
        int d = offs[node + 1] - start;
        int dl = min(d, 64);
        int c = csr[start + lane];                 // csr padded +64
        float xs = x[node * 8 + (lane & 7)];

        int s0 = __shfl(c, g), s1 = __shfl(c, g + 32);
        float4 w0 = xv[(size_t)((g      < dl) ? s0 : 0) * 2 + fh];
        float4 w1v = xv[(size_t)((g + 32 < dl) ? s1 : 0) * 2 + fh];
        float m0 = (g < dl) ? 1.f : 0.f;
        float m1f = (g + 32 < dl) ? 1.f : 0.f;
        float ax = m0 * w0.x + m1f * w1v.x;
        float ay = m0 * w0.y + m1f * w1v.y;
        float az = m0 * w0.z + m1f * w1v.z;
        float aw = m0 * w0.w + m1f * w1v.w;
        for (int i = g + 64; i < d; i += 32) {     // rare tail
            int s = csr[start + i];
            float4 w = xv[(size_t)s * 2 + fh];
            ax += w.x; ay += w.y; az += w.z; aw += w.w;
        }
#define RED1(X) X += __shfl_xor(X, 2); X += __shfl_xor(X, 4); X += __shfl_xor(X, 8); \
                X += __shfl_xor(X, 16); X += __shfl_xor(X, 32);
        RED1(ax) RED1(ay) RED1(az) RED1(aw)
#undef RED1
        float di = deginv[node];
        ax *= di; ay *= di; az *= di; aw *= di;

        float h = c1;
#pragma unroll
        for (int k = 0; k < 8; k++) {
            float comp = ((k & 3) == 0) ? ax : ((k & 3) == 1) ? ay : ((k & 3) == 2) ? az : aw;
            float a  = __shfl(comp, k >> 2);
            float xr = __shfl(xs, k);
            h = fmaf(a, w1lr[k], fmaf(xr, w1rr[k], h));
        }
        h1b[(size_t)node * 64 + lane] = f2b(fmaxf(h, 0.f));
    }
}

// ---- Dense 1 (MFMA): h1 (bf16) -> t2 = h1@(w2l*k2) bf16, r2 = h1@(w2r*k2)+c2 fp32 ----

__global__ __launch_bounds__(64, 2) void k_dense1(
    const bf16* __restrict__ h1b,
    const float* __restrict__ w2l, const float* __restrict__ w2r,
    const float* __restrict__ b2,
    const float* __restrict__ g2, const float* __restrict__ bb2,
    const float* __restrict__ m2, const float* __restrict__ v2,
    bf16* __restrict__ t2, float* __restrict__ r2)
{
    int lane = threadIdx.x;
    int cn = lane & 15, kg = lane >> 4;

    bf16x8 BL[4][2], BR[4][2];
    float c2c[4];
#pragma unroll
    for (int ct = 0; ct < 4; ct++) {
        int col = ct * 16 + cn;
        float k2 = g2[col] * rsqrtf(v2[col] + 1e-5f);
        c2c[ct] = (b2[col] - m2[col]) * k2 + bb2[col];
#pragma unroll
        for (int kh = 0; kh < 2; kh++) {
#pragma unroll
            for (int j = 0; j < 8; j++) {
                int k = kh * 32 + kg * 8 + j;
                BL[ct][kh][j] = f2bs(w2l[k * 64 + col] * k2);
                BR[ct][kh][j] = f2bs(w2r[k * 64 + col] * k2);
            }
        }
    }

    const uint4* hv = (const uint4*)h1b;   // row stride = 8 uint4 (64 bf16)
    int ntiles = NNODES / 16;              // 6250
    for (int t = blockIdx.x; t < ntiles; t += gridDim.x) {
        int row = t * 16 + cn;
        uint4 a0u = hv[(size_t)row * 8 + kg];
        uint4 a1u = hv[(size_t)row * 8 + 4 + kg];
        bf16x8 a0 = *reinterpret_cast<bf16x8*>(&a0u);
        bf16x8 a1 = *reinterpret_cast<bf16x8*>(&a1u);
#pragma unroll
        for (int ct = 0; ct < 4; ct++) {
            f32x4 accT = {0.f, 0.f, 0.f, 0.f};
            f32x4 accR = {c2c[ct], c2c[ct], c2c[ct], c2c[ct]};
            accT = __builtin_amdgcn_mfma_f32_16x16x32_bf16(a0, BL[ct][0], accT, 0, 0, 0);
            accT = __builtin_amdgcn_mfma_f32_16x16x32_bf16(a1, BL[ct][1], accT, 0, 0, 0);
            accR = __builtin_amdgcn_mfma_f32_16x16x32_bf16(a0, BR[ct][0], accR, 0, 0, 0);
            accR = __builtin_amdgcn_mfma_f32_16x16x32_bf16(a1, BR[ct][1], accR, 0, 0, 0);
#pragma unroll
            for (int r = 0; r < 4; r++) {
                int node = t * 16 + kg * 4 + r;
                int col  = ct * 16 + cn;
                t2[(size_t)node * 64 + col] = f2b(accT[r]);
                r2[(size_t)node * 64 + col] = accR[r];
            }
        }
    }
}

// ---- Gather 2: 4 waves/block, each wave one node. t2-gather + r2 + ReLU -> h2 ----

__global__ __launch_bounds__(256) void k_gather2(
    const bf16* __restrict__ t2, const float* __restrict__ r2,
    const int* __restrict__ csr, const int* __restrict__ offs,
    const float* __restrict__ deginv,
    bf16* __restrict__ h2b)
{
    int lane = threadIdx.x & 63, wid = threadIdx.x >> 6;
    int fq = lane & 7;       // feature octet
    int g  = lane >> 3;      // 8 edge slots
    const uint4* t2v = (const uint4*)t2;

    for (int node = blockIdx.x * 4 + wid; node < NNODES; node += gridDim.x * 4) {
        int start = offs[node];
        int d = offs[node + 1] - start;
        int dl = min(d, 64);
        int c = csr[start + lane];
        float r2v = r2[(size_t)node * 64 + lane];
        float di = deginv[node];

        int s;
        s = __shfl(c, g     ); uint4 w0 = t2v[(size_t)((g      < dl) ? s : 0) * 8 + fq];
        s = __shfl(c, g +  8); uint4 w1 = t2v[(size_t)((g +  8 < dl) ? s : 0) * 8 + fq];
        s = __shfl(c, g + 16); uint4 w2 = t2v[(size_t)((g + 16 < dl) ? s : 0) * 8 + fq];
        s = __shfl(c, g + 24); uint4 w3 = t2v[(size_t)((g + 24 < dl) ? s : 0) * 8 + fq];
        s = __shfl(c, g + 32); uint4 w4 = t2v[(size_t)((g + 32 < dl) ? s : 0) * 8 + fq];
        s = __shfl(c, g + 40); uint4 w5 = t2v[(size_t)((g + 40 < dl) ? s : 0) * 8 + fq];
        s = __shfl(c, g + 48); uint4 w6 = t2v[(size_t)((g + 48 < dl) ? s : 0) * 8 + fq];
        s = __shfl(c, g + 56); uint4 w7 = t2v[(size_t)((g + 56 < dl) ? s : 0) * 8 + fq];

        float a0 = 0, a1 = 0, a2 = 0, a3 = 0, a4 = 0, a5 = 0, a6 = 0, a7 = 0;
#define CONS(W, M) \
        a0 = fmaf(M, lo2f(W.x), a0); a1 = fmaf(M, hi2f(W.x), a1); \
        a2 = fmaf(M, lo2f(W.y), a2); a3 = fmaf(M, hi2f(W.y), a3); \
        a4 = fmaf(M, lo2f(W.z), a4); a5 = fmaf(M, hi2f(W.z), a5); \
        a6 = fmaf(M, lo2f(W.w), a6); a7 = fmaf(M, hi2f(W.w), a7);
        CONS(w0, (g      < dl) ? 1.f : 0.f)
        CONS(w1, (g +  8 < dl) ? 1.f : 0.f)
        CONS(w2, (g + 16 < dl) ? 1.f : 0.f)
        CONS(w3, (g + 24 < dl) ? 1.f : 0.f)
        CONS(w4, (g + 32 < dl) ? 1.f : 0.f)
        CONS(w5, (g + 40 < dl) ? 1.f : 0.f)
        CONS(w6, (g + 48 < dl) ? 1.f : 0.f)
        CONS(w7, (g + 56 < dl) ? 1.f : 0.f)
        for (int i = g + 64; i < d; i += 8) {       // rare tail
            int ss = csr[start + i];
            uint4 w = t2v[(size_t)ss * 8 + fq];
            CONS(w, 1.f)
        }
#undef CONS
#define RED2(X) X += __shfl_xor(X, 8); X += __shfl_xor(X, 16); X += __shfl_xor(X, 32);
        RED2(a0) RED2(a1) RED2(a2) RED2(a3) RED2(a4) RED2(a5) RED2(a6) RED2(a7)
#undef RED2
        float u = sel8(lane >> 3, a0, a1, a2, a3, a4, a5, a6, a7);
        int srcl = ((lane & 7) << 3) | (lane >> 3);
        float v = __shfl(u, srcl);

        h2b[(size_t)node * 64 + lane] = f2b(fmaxf(v * di + r2v, 0.f));
    }
}

// ---- Dense 2 (MFMA): h2 (bf16) -> [t3 | r3] = h2 @ [w3l | w3r] (+b3 on r3) ----

__global__ __launch_bounds__(64, 2) void k_dense2(
    const bf16* __restrict__ h2b,
    const float* __restrict__ w3l, const float* __restrict__ w3r,
    const float* __restrict__ b3,
    bf16* __restrict__ t3, float* __restrict__ r3)
{
    int lane = threadIdx.x;
    int cn = lane & 15, kg = lane >> 4;

    bf16x8 Bf[4][2];
    float cini[4];
#pragma unroll
    for (int ct = 0; ct < 4; ct++) {
        int col = ct * 16 + cn;               // 0..63 over [w3l | w3r]
        const float* W = (ct < 2) ? w3l : w3r;
        int cc = col & 31;
        cini[ct] = (ct < 2) ? 0.f : b3[cc];
#pragma unroll
        for (int kh = 0; kh < 2; kh++) {
#pragma unroll
            for (int j = 0; j < 8; j++) {
                int k = kh * 32 + kg * 8 + j;
                Bf[ct][kh][j] = f2bs(W[k * 32 + cc]);
            }
        }
    }

    const uint4* hv = (const uint4*)h2b;
    int ntiles = NNODES / 16;
    for (int t = blockIdx.x; t < ntiles; t += gridDim.x) {
        int row = t * 16 + cn;
        uint4 a0u = hv[(size_t)row * 8 + kg];
        uint4 a1u = hv[(size_t)row * 8 + 4 + kg];
        bf16x8 a0 = *reinterpret_cast<bf16x8*>(&a0u);
        bf16x8 a1 = *reinterpret_cast<bf16x8*>(&a1u);
#pragma unroll
        for (int ct = 0; ct < 4; ct++) {
            f32x4 acc = {cini[ct], cini[ct], cini[ct], cini[ct]};
            acc = __builtin_amdgcn_mfma_f32_16x16x32_bf16(a0, Bf[ct][0], acc, 0, 0, 0);
            acc = __builtin_amdgcn_mfma_f32_16x16x32_bf16(a1, Bf[ct][1], acc, 0, 0, 0);
#pragma unroll
            for (int r = 0; r < 4; r++) {
                int node = t * 16 + kg * 4 + r;
                if (ct < 2) t3[(size_t)node * 32 + ct * 16 + cn] = f2b(acc[r]);
                else        r3[(size_t)node * 32 + (ct - 2) * 16 + cn] = acc[r];
            }
        }
    }
}

// ---- Layer 3: gather t3 (bf16) -> relu(agg+r3) -> fc -> sigmoid ----

__global__ __launch_bounds__(256) void k_layer3(
    const bf16* __restrict__ t3, const float* __restrict__ r3,
    const int* __restrict__ csr, const int* __restrict__ offs,
    const float* __restrict__ deginv,
    const float* __restrict__ fcw, const float* __restrict__ fcb,
    float* __restrict__ out)
{
    int tid = threadIdx.x;
    int lane = tid & 63;
    int node = blockIdx.x * 4 + (tid >> 6);
    if (node >= NNODES) return;

    int o = lane & 31;
    float fcwv = fcw[o];
    float fcbv = fcb[0];

    int start = offs[node];
    int d = offs[node + 1] - start;
    int dl = min(d, 64);
    int c = csr[start + lane];
    float r3v = r3[(size_t)node * 32 + o];

    int fq = lane & 3;
    int g  = lane >> 2;
    const uint4* t3v = (const uint4*)t3;

    int   si[4];
    float mk[4];
#pragma unroll
    for (int t = 0; t < 4; t++) {
        int i = g + 16 * t;
        int s = __shfl(c, i);
        mk[t] = (i < dl) ? 1.f : 0.f;
        si[t] = (i < dl) ? s : 0;
    }
    uint4 w0 = t3v[(size_t)si[0] * 4 + fq];
    uint4 w1 = t3v[(size_t)si[1] * 4 + fq];
    uint4 w2 = t3v[(size_t)si[2] * 4 + fq];
    uint4 w3 = t3v[(size_t)si[3] * 4 + fq];

    float a0 = 0, a1 = 0, a2 = 0, a3 = 0, a4 = 0, a5 = 0, a6 = 0, a7 = 0;
#define CONS(W, M) \
    a0 = fmaf(M, lo2f(W.x), a0); a1 = fmaf(M, hi2f(W.x), a1); \
    a2 = fmaf(M, lo2f(W.y), a2); a3 = fmaf(M, hi2f(W.y), a3); \
    a4 = fmaf(M, lo2f(W.z), a4); a5 = fmaf(M, hi2f(W.z), a5); \
    a6 = fmaf(M, lo2f(W.w), a6); a7 = fmaf(M, hi2f(W.w), a7);
    CONS(w0, mk[0]) CONS(w1, mk[1]) CONS(w2, mk[2]) CONS(w3, mk[3])
    for (int i = g + 64; i < d; i += 16) {
        int s = csr[start + i];
        uint4 w = t3v[(size_t)s * 4 + fq];
        CONS(w, 1.f)
    }
#undef CONS
#define RED3(X) X += __shfl_xor(X, 4); X += __shfl_xor(X, 8); X += __shfl_xor(X, 16); X += __shfl_xor(X, 32);
    RED3(a0) RED3(a1) RED3(a2) RED3(a3) RED3(a4) RED3(a5) RED3(a6) RED3(a7)
#undef RED3
    float u = sel8((lane >> 2) & 7, a0, a1, a2, a3, a4, a5, a6, a7);
    int srcl = ((lane & 7) << 2) | ((lane >> 3) & 3);
    float v = __shfl(u, srcl);

    float h3 = fmaxf(v * deginv[node] + r3v, 0.f);

    float p = h3 * fcwv;
    p += __shfl_xor(p, 1);
    p += __shfl_xor(p, 2);
    p += __shfl_xor(p, 4);
    p += __shfl_xor(p, 8);
    p += __shfl_xor(p, 16);
    if (lane == 0) {
        float z = p + fcbv;
        out[node] = 1.0f / (1.0f + expf(-z));
    }
}

// ---------------- launch ----------------

extern "C" void kernel_launch(void* const* d_in, const int* in_sizes, int n_in,
                              void* d_out, int out_size, void* d_ws, size_t ws_size,
                              hipStream_t stream)
{
    const float* x   = (const float*)d_in[0];
    const int*   ei  = (const int*)d_in[1];
    const int*   src = ei;
    const int*   dst = ei + NEDGES;
    const float* w1l = (const float*)d_in[2];
    const float* w1r = (const float*)d_in[3];
    const float* b1  = (const float*)d_in[4];
    const float* g1  = (const float*)d_in[5];
    const float* bb1 = (const float*)d_in[6];
    const float* m1  = (const float*)d_in[7];
    const float* v1  = (const float*)d_in[8];
    const float* w2l = (const float*)d_in[9];
    const float* w2r = (const float*)d_in[10];
    const float* b2  = (const float*)d_in[11];
    const float* g2  = (const float*)d_in[12];
    const float* bb2 = (const float*)d_in[13];
    const float* m2  = (const float*)d_in[14];
    const float* v2  = (const float*)d_in[15];
    const float* w3l = (const float*)d_in[16];
    const float* w3r = (const float*)d_in[17];
    const float* b3  = (const float*)d_in[18];
    const float* fcw = (const float*)d_in[19];
    const float* fcb = (const float*)d_in[20];

    char* ws = (char*)d_ws;
    size_t off = 0;
    auto alloc = [&](size_t bytes) -> void* {
        void* p = ws + off;
        off += (bytes + 255) & ~(size_t)255;
        return p;
    };
    int*   offs   = (int*)alloc((size_t)(NNODES + 1) * 4);
    int*   bs     = (int*)alloc((size_t)NCHB * 4);
    int*   bse    = (int*)alloc((size_t)(NCHB + 1) * 4);
    int*   histT  = (int*)alloc((size_t)NCHB * NBLK * 4);
    float* deginv = (float*)alloc((size_t)NNODES * 4);
    int*   csr    = (int*)alloc((size_t)(NEDGES + 64) * 4);  // +64 pad
    bf16*  h1b    = (bf16*)alloc((size_t)NNODES * 64 * 2);
    bf16*  t2     = (bf16*)alloc((size_t)NNODES * 64 * 2);
    float* r2     = (float*)alloc((size_t)NNODES * 64 * 4);
    bf16*  h2b    = (bf16*)alloc((size_t)NNODES * 64 * 2);
    bf16*  t3     = (bf16*)alloc((size_t)NNODES * 32 * 2);
    float* r3     = (float*)alloc((size_t)NNODES * 32 * 4);
    int*   tmp    = (int*)r2;   // aliased: consumed by k_bucket before k_dense1 writes r2

    hipMemsetAsync(bs, 0, (size_t)NCHB * 4, stream);

    k_hist2<<<NBLK, 256, 0, stream>>>((const int4*)dst, histT, bs);
    k_scanbs<<<1, 512, 0, stream>>>(bs, bse, offs);
    k_scanhist<<<NCHB, 256, 0, stream>>>(histT, bse);
    k_scatter2<<<NBLK, 256, 0, stream>>>((const int4*)src, (const int4*)dst, histT, tmp);
    k_bucket<<<NCHB, 256, 0, stream>>>(tmp, bse, offs, deginv, csr);

    k_gather1<<<4096, 256, 0, stream>>>(x, csr, offs, deginv,
                                        w1l, w1r, b1, g1, bb1, m1, v1, h1b);
    k_dense1<<<4096, 64, 0, stream>>>(h1b, w2l, w2r, b2, g2, bb2, m2, v2, t2, r2);
    k_gather2<<<4096, 256, 0, stream>>>(t2, r2, csr, offs, deginv, h2b);
    k_dense2<<<4096, 64, 0, stream>>>(h2b, w3l, w3r, b3, t3, r3);
    k_layer3<<<(NNODES + 3) / 4, 256, 0, stream>>>(t3, r3, csr, offs, deginv,
                                                   fcw, fcb, (float*)d_out);
}